// Round 1
// baseline (10195.721 us; speedup 1.0000x reference)
//
#include <hip/hip_runtime.h>
#include <math.h>

#define B_ 8
#define T_ 16000
#define RES 64
#define GATE 128
#define SKIPC 256
#define OUTC 256
#define NLAYERS 20

#define TT 128
#define NTB (T_/TT)      // 125
#define TT2 64
#define NTB2 (T_/TT2)    // 250

// ---------------- head-in: h = 2*(w_pre0 @ shift(x,1) + b_pre0) ----------------
__global__ __launch_bounds__(256) void k_head_in(
    const float* __restrict__ x, const float* __restrict__ w,
    const float* __restrict__ bias, float* __restrict__ h)
{
  int bb = blockIdx.x / NTB;
  int t0 = (blockIdx.x % NTB) * TT;
  int tid = threadIdx.x;
  int c = tid & (TT-1);
  int rg = __builtin_amdgcn_readfirstlane(tid >> 7);   // 0..1, wave-uniform
  __shared__ float sx[64][TT];
  float acc[32];
#pragma unroll
  for (int i = 0; i < 32; ++i) acc[i] = 0.f;
  const float* xb = x + (size_t)bb * OUTC * T_;
  for (int kc = 0; kc < 4; ++kc) {
    if (kc) __syncthreads();
    for (int i = tid; i < 64*TT; i += 256) {
      int k = i >> 7, cc = i & (TT-1);
      int t = t0 + cc - 1;
      sx[k][cc] = (t >= 0) ? xb[(size_t)(kc*64+k)*T_ + t] : 0.f;
    }
    __syncthreads();
    for (int k = 0; k < 64; ++k) {
      float v = sx[k][c];
#pragma unroll
      for (int j = 0; j < 32; ++j)
        acc[j] += w[(rg*32+j)*OUTC + kc*64 + k] * v;
    }
  }
  float* hb = h + (size_t)bb * RES * T_;
#pragma unroll
  for (int j = 0; j < 32; ++j) {
    int r = rg*32 + j;
    hb[(size_t)r*T_ + t0 + c] = 2.f * (acc[j] + bias[r]);
  }
}

// ---------------- per-layer fused kernel ----------------
__global__ __launch_bounds__(256) void k_layer(
    const float* __restrict__ hin, float* __restrict__ hout,
    float* __restrict__ skip,
    const float* __restrict__ wdp, const float* __restrict__ wdc,
    const float* __restrict__ bh,
    const float* __restrict__ wr, const float* __restrict__ br,
    const float* __restrict__ wsk, const float* __restrict__ bsk,
    int d, int first)
{
  int bb = blockIdx.x / NTB;
  int t0 = (blockIdx.x % NTB) * TT;
  int tid = threadIdx.x;
  int c = tid & (TT-1);
  int rg = __builtin_amdgcn_readfirstlane(tid >> 7);   // 0..1, wave-uniform
  __shared__ float sh[RES][TT];
  __shared__ float shp[RES][TT];

  const float* hb = hin + (size_t)bb * RES * T_;
  for (int i = tid; i < RES*TT; i += 256) {
    int k = i >> 7, cc = i & (TT-1);
    sh[k][cc] = hb[(size_t)k*T_ + t0 + cc];
    int tp = t0 + cc - d;
    shp[k][cc] = (tp >= 0) ? hb[(size_t)k*T_ + tp] : 0.f;
  }
  __syncthreads();

  // a = wdp @ h_pre + wdc @ h + bh ; gate
  float gv[32];
  int j0 = rg * 32;
#pragma unroll
  for (int ch = 0; ch < 4; ++ch) {
    float at[8], as[8];
#pragma unroll
    for (int u = 0; u < 8; ++u) { at[u] = 0.f; as[u] = 0.f; }
    for (int k = 0; k < RES; ++k) {
      float hv = sh[k][c];
      float hp = shp[k][c];
#pragma unroll
      for (int u = 0; u < 8; ++u) {
        int jj = j0 + ch*8 + u;
        at[u] += wdp[jj*RES + k] * hp + wdc[jj*RES + k] * hv;
        as[u] += wdp[(jj+64)*RES + k] * hp + wdc[(jj+64)*RES + k] * hv;
      }
    }
#pragma unroll
    for (int u = 0; u < 8; ++u) {
      int jj = j0 + ch*8 + u;
      float tv = tanhf(at[u] + bh[jj]);
      float sv = 1.f / (1.f + expf(-(as[u] + bh[jj+64])));
      gv[ch*8 + u] = tv * sv;
    }
  }
  __syncthreads();                // everyone done reading shp
  float (*sg)[TT] = shp;          // reuse shp storage for g
#pragma unroll
  for (int i = 0; i < 32; ++i) sg[j0 + i][c] = gv[i];
  __syncthreads();

  // res: h_out = h_in + w_res @ g + b_res
  float* hob = hout + (size_t)bb * RES * T_;
  for (int ch = 0; ch < 4; ++ch) {
    float acc[8];
#pragma unroll
    for (int u = 0; u < 8; ++u) acc[u] = 0.f;
    for (int k = 0; k < RES; ++k) {
      float gk = sg[k][c];
#pragma unroll
      for (int u = 0; u < 8; ++u)
        acc[u] += wr[(rg*32 + ch*8 + u)*RES + k] * gk;
    }
#pragma unroll
    for (int u = 0; u < 8; ++u) {
      int r = rg*32 + ch*8 + u;
      hob[(size_t)r*T_ + t0 + c] = sh[r][c] + acc[u] + br[r];
    }
  }

  // skip += w_skip @ g + b_skip
  float* skb = skip + (size_t)bb * SKIPC * T_;
  for (int ch = 0; ch < 8; ++ch) {
    float acc[16];
#pragma unroll
    for (int u = 0; u < 16; ++u) acc[u] = 0.f;
    for (int k = 0; k < RES; ++k) {
      float gk = sg[k][c];
#pragma unroll
      for (int u = 0; u < 16; ++u)
        acc[u] += wsk[(rg*128 + ch*16 + u)*RES + k] * gk;
    }
#pragma unroll
    for (int u = 0; u < 16; ++u) {
      int s = rg*128 + ch*16 + u;
      float v = acc[u] + bsk[s];
      if (!first) v += skb[(size_t)s*T_ + t0 + c];
      skb[(size_t)s*T_ + t0 + c] = v;
    }
  }
}

// ---------------- head-out: relu -> w_relu -> relu -> w_out -> softmax ----------------
__global__ __launch_bounds__(256) void k_head_out(
    float* __restrict__ io,    // skip in, softmax out (in-place)
    const float* __restrict__ wrl, const float* __restrict__ brl,
    const float* __restrict__ wo, const float* __restrict__ bo)
{
  int bb = blockIdx.x / NTB2;
  int t0 = (blockIdx.x % NTB2) * TT2;
  int tid = threadIdx.x;
  int c = tid & 63;
  int rg = __builtin_amdgcn_readfirstlane(tid >> 6);   // 0..3, wave-uniform
  __shared__ float s1[256][TT2];
  __shared__ float s2[256][TT2];
  __shared__ float pred[4][TT2];

  float* iob = io + (size_t)bb * OUTC * T_;
  for (int i = tid; i < 256*TT2; i += 256) {
    int ch = i >> 6, cc = i & 63;
    s1[ch][cc] = fmaxf(iob[(size_t)ch*T_ + t0 + cc], 0.f);
  }
  __syncthreads();

  // o2 = relu(wrl @ s1 + brl) -> s2
  for (int chnk = 0; chnk < 4; ++chnk) {
    float acc[16];
#pragma unroll
    for (int u = 0; u < 16; ++u) acc[u] = 0.f;
    for (int k = 0; k < 256; ++k) {
      float v = s1[k][c];
#pragma unroll
      for (int u = 0; u < 16; ++u)
        acc[u] += wrl[(rg*64 + chnk*16 + u)*256 + k] * v;
    }
#pragma unroll
    for (int u = 0; u < 16; ++u) {
      int r = rg*64 + chnk*16 + u;
      s2[r][c] = fmaxf(acc[u] + brl[r], 0.f);
    }
  }
  __syncthreads();

  // logits = wo @ s2 + bo, kept in regs
  float lmax = -1e30f;
  float lv[64];
#pragma unroll
  for (int chnk = 0; chnk < 4; ++chnk) {
    float acc[16];
#pragma unroll
    for (int u = 0; u < 16; ++u) acc[u] = 0.f;
    for (int k = 0; k < 256; ++k) {
      float v = s2[k][c];
#pragma unroll
      for (int u = 0; u < 16; ++u)
        acc[u] += wo[(rg*64 + chnk*16 + u)*256 + k] * v;
    }
#pragma unroll
    for (int u = 0; u < 16; ++u) {
      int r = rg*64 + chnk*16 + u;
      float l = acc[u] + bo[r];
      lv[chnk*16 + u] = l;
      lmax = fmaxf(lmax, l);
    }
  }
  pred[rg][c] = lmax;
  __syncthreads();
  float m = fmaxf(fmaxf(pred[0][c], pred[1][c]), fmaxf(pred[2][c], pred[3][c]));
  float psum = 0.f;
#pragma unroll
  for (int i = 0; i < 64; ++i) { lv[i] = expf(lv[i] - m); psum += lv[i]; }
  __syncthreads();               // everyone read pred (max) before overwrite
  pred[rg][c] = psum;
  __syncthreads();
  float S = pred[0][c] + pred[1][c] + pred[2][c] + pred[3][c];
  float rinv = 1.f / S;
#pragma unroll
  for (int i = 0; i < 64; ++i) {
    int r = rg*64 + i;
    iob[(size_t)r*T_ + t0 + c] = lv[i] * rinv;
  }
}

extern "C" void kernel_launch(void* const* d_in, const int* in_sizes, int n_in,
                              void* d_out, int out_size, void* d_ws, size_t ws_size,
                              hipStream_t stream) {
  const float* x       = (const float*)d_in[0];
  const float* w_pre0  = (const float*)d_in[1];
  const float* b_pre0  = (const float*)d_in[2];
  const float* w_dil_p = (const float*)d_in[3];
  const float* w_dil_c = (const float*)d_in[4];
  const float* bias_h  = (const float*)d_in[5];
  const float* w_res   = (const float*)d_in[6];
  const float* b_res   = (const float*)d_in[7];
  const float* w_skip  = (const float*)d_in[8];
  const float* b_skip  = (const float*)d_in[9];
  const float* w_relu  = (const float*)d_in[10];
  const float* b_relu  = (const float*)d_in[11];
  const float* w_out   = (const float*)d_in[12];
  const float* b_out   = (const float*)d_in[13];

  float* out = (float*)d_out;              // also used as skip accumulator
  float* hA = (float*)d_ws;
  float* hB = hA + (size_t)B_ * RES * T_;

  k_head_in<<<B_ * NTB, 256, 0, stream>>>(x, w_pre0, b_pre0, hA);

  const float* hin = hA;
  float* houtp = hB;
  for (int l = 0; l < NLAYERS; ++l) {
    int d = 1 << (l % 10);
    k_layer<<<B_ * NTB, 256, 0, stream>>>(
        hin, houtp, out,
        w_dil_p + (size_t)l*GATE*RES, w_dil_c + (size_t)l*GATE*RES,
        bias_h + (size_t)l*GATE,
        w_res + (size_t)l*RES*RES, b_res + (size_t)l*RES,
        w_skip + (size_t)l*SKIPC*RES, b_skip + (size_t)l*SKIPC,
        d, l == 0 ? 1 : 0);
    const float* tmp = hin;
    hin = houtp;
    houtp = (float*)tmp;
  }

  k_head_out<<<B_ * NTB2, 256, 0, stream>>>(out, w_relu, b_relu, w_out, b_out);
}

// Round 2
// 8143.833 us; speedup vs baseline: 1.2520x; 1.2520x over previous
//
#include <hip/hip_runtime.h>
#include <math.h>

#define B_ 8
#define T_ 16000
#define RES 64
#define GATE 128
#define SKIPC 256
#define OUTC 256
#define NLAYERS 20

#define TT 128
#define NTB (T_/TT)      // 125
#define TT2 64
#define NTB2 (T_/TT2)    // 250

// ---------------- head-in: h = 2*(w_pre0 @ shift(x,1) + b_pre0) ----------------
// 512 threads: 4 row-groups x 128 columns; each group computes 16 of 64 rows.
__global__ __launch_bounds__(512) void k_head_in(
    const float* __restrict__ x, const float* __restrict__ w,
    const float* __restrict__ bias, float* __restrict__ h)
{
  int bb = blockIdx.x / NTB;
  int t0 = (blockIdx.x % NTB) * TT;
  int tid = threadIdx.x;
  int c = tid & (TT-1);
  int rg = __builtin_amdgcn_readfirstlane(tid >> 7);   // 0..3, wave-uniform
  __shared__ float sx[64][TT];
  float acc[16];
#pragma unroll
  for (int i = 0; i < 16; ++i) acc[i] = 0.f;
  const float* xb = x + (size_t)bb * OUTC * T_;
  for (int kc = 0; kc < 4; ++kc) {
    if (kc) __syncthreads();
    for (int i = tid; i < 64*TT; i += 512) {
      int k = i >> 7, cc = i & (TT-1);
      int t = t0 + cc - 1;
      sx[k][cc] = (t >= 0) ? xb[(size_t)(kc*64+k)*T_ + t] : 0.f;
    }
    __syncthreads();
    for (int k = 0; k < 64; ++k) {
      float v = sx[k][c];
#pragma unroll
      for (int j = 0; j < 16; ++j)
        acc[j] += w[(rg*16+j)*OUTC + kc*64 + k] * v;
    }
  }
  float* hb = h + (size_t)bb * RES * T_;
#pragma unroll
  for (int j = 0; j < 16; ++j) {
    int r = rg*16 + j;
    hb[(size_t)r*T_ + t0 + c] = 2.f * (acc[j] + bias[r]);
  }
}

// ---------------- per-layer fused kernel ----------------
// 512 threads: 4 row-groups x 128 columns.
__global__ __launch_bounds__(512) void k_layer(
    const float* __restrict__ hin, float* __restrict__ hout,
    float* __restrict__ skip,
    const float* __restrict__ wdp, const float* __restrict__ wdc,
    const float* __restrict__ bh,
    const float* __restrict__ wr, const float* __restrict__ br,
    const float* __restrict__ wsk, const float* __restrict__ bsk,
    int d, int first)
{
  int bb = blockIdx.x / NTB;
  int t0 = (blockIdx.x % NTB) * TT;
  int tid = threadIdx.x;
  int c = tid & (TT-1);
  int rg = __builtin_amdgcn_readfirstlane(tid >> 7);   // 0..3, wave-uniform
  __shared__ float sh[RES][TT];
  __shared__ float shp[RES][TT];   // reused for g after the gate phase

  const float* hb = hin + (size_t)bb * RES * T_;
  for (int i = tid; i < RES*TT; i += 512) {
    int k = i >> 7, cc = i & (TT-1);
    sh[k][cc] = hb[(size_t)k*T_ + t0 + cc];
    int tp = t0 + cc - d;
    shp[k][cc] = (tp >= 0) ? hb[(size_t)k*T_ + tp] : 0.f;
  }
  __syncthreads();

  // gate: rows j0..j0+15 (tanh half) and j0+64..j0+79 (sigmoid half)
  int j0 = rg * 16;
  float at[16], as[16];
#pragma unroll
  for (int u = 0; u < 16; ++u) { at[u] = 0.f; as[u] = 0.f; }
  for (int k = 0; k < RES; ++k) {
    float hp = shp[k][c];
    float hv = sh[k][c];
#pragma unroll
    for (int u = 0; u < 16; ++u) {
      int jj = j0 + u;
      at[u] += wdp[jj*RES + k] * hp + wdc[jj*RES + k] * hv;
      as[u] += wdp[(jj+64)*RES + k] * hp + wdc[(jj+64)*RES + k] * hv;
    }
  }
  float gv[16];
#pragma unroll
  for (int u = 0; u < 16; ++u) {
    int jj = j0 + u;
    float tv = tanhf(at[u] + bh[jj]);
    float sv = 1.f / (1.f + expf(-(as[u] + bh[jj+64])));
    gv[u] = tv * sv;
  }
  __syncthreads();                // everyone done reading shp
  float (*sg)[TT] = shp;          // reuse shp storage for g
#pragma unroll
  for (int u = 0; u < 16; ++u) sg[j0 + u][c] = gv[u];
  __syncthreads();

  // res: h_out rows j0..j0+15
  float* hob = hout + (size_t)bb * RES * T_;
  {
    float ar[16];
#pragma unroll
    for (int u = 0; u < 16; ++u) ar[u] = 0.f;
    for (int k = 0; k < RES; ++k) {
      float gk = sg[k][c];
#pragma unroll
      for (int u = 0; u < 16; ++u)
        ar[u] += wr[(j0 + u)*RES + k] * gk;
    }
#pragma unroll
    for (int u = 0; u < 16; ++u) {
      int r = j0 + u;
      hob[(size_t)r*T_ + t0 + c] = sh[r][c] + ar[u] + br[r];
    }
  }

  // skip += w_skip @ g + b_skip : rows rg*64 .. rg*64+63 in 4 chunks of 16
  float* skb = skip + (size_t)bb * SKIPC * T_;
  for (int ch = 0; ch < 4; ++ch) {
    float acc[16];
#pragma unroll
    for (int u = 0; u < 16; ++u) acc[u] = 0.f;
    for (int k = 0; k < RES; ++k) {
      float gk = sg[k][c];
#pragma unroll
      for (int u = 0; u < 16; ++u)
        acc[u] += wsk[(rg*64 + ch*16 + u)*RES + k] * gk;
    }
#pragma unroll
    for (int u = 0; u < 16; ++u) {
      int s = rg*64 + ch*16 + u;
      float v = acc[u] + bsk[s];
      if (!first) v += skb[(size_t)s*T_ + t0 + c];
      skb[(size_t)s*T_ + t0 + c] = v;
    }
  }
}

// ---------------- head-out: relu -> w_relu -> relu -> w_out -> softmax ----------------
// 512 threads: 8 row-groups x 64 columns. Single LDS activation buffer,
// GEMM1 results held in registers, buffer overwritten after a sync.
__global__ __launch_bounds__(512) void k_head_out(
    float* __restrict__ io,    // skip in, softmax out (in-place)
    const float* __restrict__ wrl, const float* __restrict__ brl,
    const float* __restrict__ wo, const float* __restrict__ bo)
{
  int bb = blockIdx.x / NTB2;
  int t0 = (blockIdx.x % NTB2) * TT2;
  int tid = threadIdx.x;
  int c = tid & 63;
  int rg = __builtin_amdgcn_readfirstlane(tid >> 6);   // 0..7, wave-uniform
  __shared__ float s1[256][TT2];
  __shared__ float pred[8][TT2];

  float* iob = io + (size_t)bb * OUTC * T_;
  for (int i = tid; i < 256*TT2; i += 512) {
    int ch = i >> 6, cc = i & 63;
    s1[ch][cc] = fmaxf(iob[(size_t)ch*T_ + t0 + cc], 0.f);
  }
  __syncthreads();

  // GEMM1: o = wrl @ s1 + brl ; rows rg*32 .. rg*32+31 held in registers
  float o[32];
#pragma unroll
  for (int u = 0; u < 32; ++u) o[u] = 0.f;
  for (int k = 0; k < 256; ++k) {
    float v = s1[k][c];
#pragma unroll
    for (int u = 0; u < 32; ++u)
      o[u] += wrl[(rg*32 + u)*256 + k] * v;
  }
  __syncthreads();               // all reads of s1 done
#pragma unroll
  for (int u = 0; u < 32; ++u) {
    int r = rg*32 + u;
    s1[r][c] = fmaxf(o[u] + brl[r], 0.f);
  }
  __syncthreads();

  // GEMM2: logits rows rg*32 .. rg*32+31 in registers
  float lv[32];
#pragma unroll
  for (int u = 0; u < 32; ++u) lv[u] = 0.f;
  for (int k = 0; k < 256; ++k) {
    float v = s1[k][c];
#pragma unroll
    for (int u = 0; u < 32; ++u)
      lv[u] += wo[(rg*32 + u)*256 + k] * v;
  }
  float lmax = -1e30f;
#pragma unroll
  for (int u = 0; u < 32; ++u) {
    lv[u] += bo[rg*32 + u];
    lmax = fmaxf(lmax, lv[u]);
  }
  pred[rg][c] = lmax;
  __syncthreads();
  float m = pred[0][c];
#pragma unroll
  for (int g = 1; g < 8; ++g) m = fmaxf(m, pred[g][c]);
  float psum = 0.f;
#pragma unroll
  for (int u = 0; u < 32; ++u) { lv[u] = expf(lv[u] - m); psum += lv[u]; }
  __syncthreads();               // everyone read pred (max) before overwrite
  pred[rg][c] = psum;
  __syncthreads();
  float S = 0.f;
#pragma unroll
  for (int g = 0; g < 8; ++g) S += pred[g][c];
  float rinv = 1.f / S;
#pragma unroll
  for (int u = 0; u < 32; ++u) {
    int r = rg*32 + u;
    iob[(size_t)r*T_ + t0 + c] = lv[u] * rinv;
  }
}

extern "C" void kernel_launch(void* const* d_in, const int* in_sizes, int n_in,
                              void* d_out, int out_size, void* d_ws, size_t ws_size,
                              hipStream_t stream) {
  const float* x       = (const float*)d_in[0];
  const float* w_pre0  = (const float*)d_in[1];
  const float* b_pre0  = (const float*)d_in[2];
  const float* w_dil_p = (const float*)d_in[3];
  const float* w_dil_c = (const float*)d_in[4];
  const float* bias_h  = (const float*)d_in[5];
  const float* w_res   = (const float*)d_in[6];
  const float* b_res   = (const float*)d_in[7];
  const float* w_skip  = (const float*)d_in[8];
  const float* b_skip  = (const float*)d_in[9];
  const float* w_relu  = (const float*)d_in[10];
  const float* b_relu  = (const float*)d_in[11];
  const float* w_out   = (const float*)d_in[12];
  const float* b_out   = (const float*)d_in[13];

  float* out = (float*)d_out;              // also used as skip accumulator
  float* hA = (float*)d_ws;
  float* hB = hA + (size_t)B_ * RES * T_;

  k_head_in<<<B_ * NTB, 512, 0, stream>>>(x, w_pre0, b_pre0, hA);

  const float* hin = hA;
  float* houtp = hB;
  for (int l = 0; l < NLAYERS; ++l) {
    int d = 1 << (l % 10);
    k_layer<<<B_ * NTB, 512, 0, stream>>>(
        hin, houtp, out,
        w_dil_p + (size_t)l*GATE*RES, w_dil_c + (size_t)l*GATE*RES,
        bias_h + (size_t)l*GATE,
        w_res + (size_t)l*RES*RES, b_res + (size_t)l*RES,
        w_skip + (size_t)l*SKIPC*RES, b_skip + (size_t)l*SKIPC,
        d, l == 0 ? 1 : 0);
    const float* tmp = hin;
    hin = houtp;
    houtp = (float*)tmp;
  }

  k_head_out<<<B_ * NTB2, 512, 0, stream>>>(out, w_relu, b_relu, w_out, b_out);
}

// Round 4
// 2319.404 us; speedup vs baseline: 4.3958x; 3.5112x over previous
//
#include <hip/hip_runtime.h>
#include <math.h>

#define B_ 8
#define T_ 16000
#define NBT 250          // time-blocks of 64 cols

typedef __attribute__((ext_vector_type(8))) short bf16x8;
typedef __attribute__((ext_vector_type(4))) float f32x4;

__device__ __forceinline__ unsigned short f2bf(float f){
  unsigned u = __float_as_uint(f);
  u += 0x7fffu + ((u >> 16) & 1u);          // RNE to bf16
  return (unsigned short)(u >> 16);
}
__device__ __forceinline__ float bf2f(unsigned short s){
  return __uint_as_float(((unsigned)s) << 16);
}
__device__ __forceinline__ void split2(float v, unsigned short& hi, unsigned short& lo){
  hi = f2bf(v);
  lo = f2bf(v - bf2f(hi));
}

#define MFMA(a,b,c) __builtin_amdgcn_mfma_f32_16x16x32_bf16((a),(b),(c),0,0,0)

// ---------------- weight split prep ----------------
__global__ void k_split(const float* __restrict__ src, short* __restrict__ hi,
                        short* __restrict__ lo, int n){
  int idx = blockIdx.x * 256 + threadIdx.x;
  if (idx < n){
    unsigned short h, l; split2(src[idx], h, l);
    hi[idx] = (short)h; lo[idx] = (short)l;
  }
}
// gate weights: Wg[l][row][k] : k<64 -> wdp[l][row][k], else wdc[l][row][k-64]
__global__ void k_split_gate(const float* __restrict__ wdp, const float* __restrict__ wdc,
                             short* __restrict__ hi, short* __restrict__ lo){
  int idx = blockIdx.x * 256 + threadIdx.x;
  if (idx < 20*128*128){
    int l   = idx >> 14;
    int rem = idx & 16383;
    int row = rem >> 7;
    int k   = rem & 127;
    float v = (k < 64) ? wdp[(l*128 + row)*64 + k] : wdc[(l*128 + row)*64 + (k-64)];
    unsigned short h, lo16; split2(v, h, lo16);
    hi[idx] = (short)h; lo[idx] = (short)lo16;
  }
}

// ---------------- head-in: h = 2*(w_pre0 @ shift(x,1) + b) ----------------
__global__ __launch_bounds__(512) void k_head_in(
    const float* __restrict__ x, const short* __restrict__ wph,
    const short* __restrict__ wpl, const float* __restrict__ bias,
    float* __restrict__ h)
{
  __shared__ short SXh[64*256], SXl[64*256];
  const int tid = threadIdx.x;
  const int bb = blockIdx.x / NBT;
  const int t0 = (blockIdx.x % NBT) * 64;
  const int lane = tid & 63, w = tid >> 6;
  const int l16 = lane & 15, l4 = lane >> 4;

  const float* xb = x + (size_t)bb * 256 * T_;
  {
    int col = lane;
    int t = t0 + col - 1;
#pragma unroll
    for (int p = 0; p < 16; ++p){
      int k0 = w*32 + p*2;
      float v0 = (t >= 0) ? xb[(size_t)k0*T_ + t] : 0.f;
      float v1 = (t >= 0) ? xb[(size_t)(k0+1)*T_ + t] : 0.f;
      unsigned short h0,l0,h1,l1; split2(v0,h0,l0); split2(v1,h1,l1);
      int idx = col*256 + (k0 ^ ((col & 15) << 3));
      ((unsigned int*)SXh)[idx>>1] = (unsigned)h0 | ((unsigned)h1 << 16);
      ((unsigned int*)SXl)[idx>>1] = (unsigned)l0 | ((unsigned)l1 << 16);
    }
  }
  __syncthreads();

  const int mi = w & 3, nh = w >> 2;
  const int rowA = mi*16 + l16;
  bf16x8 Ah[8], Al[8];
#pragma unroll
  for (int kb = 0; kb < 8; ++kb){
    int ko = kb*32 + l4*8;
    Ah[kb] = *(const bf16x8*)(wph + (size_t)rowA*256 + ko);
    Al[kb] = *(const bf16x8*)(wpl + (size_t)rowA*256 + ko);
  }
  float* hb = h + (size_t)bb * 64 * T_;
#pragma unroll
  for (int nt = 0; nt < 2; ++nt){
    int col = (nh*2 + nt)*16 + l16;
    f32x4 acc = {0.f,0.f,0.f,0.f};
#pragma unroll
    for (int kb = 0; kb < 8; ++kb){
      int ko = (kb*32 + l4*8) ^ (l16 << 3);
      bf16x8 bhv = *(const bf16x8*)&SXh[col*256 + ko];
      bf16x8 blv = *(const bf16x8*)&SXl[col*256 + ko];
      acc = MFMA(Ah[kb], bhv, acc);
      acc = MFMA(Ah[kb], blv, acc);
      acc = MFMA(Al[kb], bhv, acc);
    }
    int t = t0 + col;
#pragma unroll
    for (int r = 0; r < 4; ++r){
      int rr = mi*16 + l4*4 + r;
      hb[(size_t)rr*T_ + t] = 2.f*(acc[r] + bias[rr]);
    }
  }
}

// ---------------- per-layer fused kernel (MFMA) ----------------
__global__ __launch_bounds__(512) void k_layer(
    const float* __restrict__ hin, float* __restrict__ hout,
    float* __restrict__ skip,
    const short* __restrict__ wgh, const short* __restrict__ wgl,
    const short* __restrict__ wrh, const short* __restrict__ wrlo,
    const short* __restrict__ wsh, const short* __restrict__ wslo,
    const float* __restrict__ bh, const float* __restrict__ br,
    const float* __restrict__ bsk, int d, int first)
{
  __shared__ short SHh[64*128], SHl[64*128];   // [col][k] k<64=h_pre, k>=64=h
  __shared__ short SGh[64*64],  SGl[64*64];    // [col][kg] g
  const int tid = threadIdx.x;
  const int bb = blockIdx.x / NBT;
  const int t0 = (blockIdx.x % NBT) * 64;
  const int lane = tid & 63, w = tid >> 6;
  const int l16 = lane & 15, l4 = lane >> 4;

  const float* hb = hin + (size_t)bb * 64 * T_;
  // stage h -> SH  (wave w stages k rows w*16 .. w*16+15)
  {
    int col = lane;
#pragma unroll
    for (int p = 0; p < 8; ++p){
      int k0 = w*16 + p*2;
      int hr0 = k0 & 63, hr1 = (k0+1) & 63;
      int t = t0 + col - ((k0 < 64) ? d : 0);
      float v0 = (t >= 0) ? hb[(size_t)hr0*T_ + t] : 0.f;
      float v1 = (t >= 0) ? hb[(size_t)hr1*T_ + t] : 0.f;
      unsigned short h0,l0,h1,l1; split2(v0,h0,l0); split2(v1,h1,l1);
      int idx = col*128 + (k0 ^ ((col & 15) << 3));
      ((unsigned int*)SHh)[idx>>1] = (unsigned)h0 | ((unsigned)h1 << 16);
      ((unsigned int*)SHl)[idx>>1] = (unsigned)l0 | ((unsigned)l1 << 16);
    }
  }
  __syncthreads();

  const int mi = w & 3, nh = w >> 2;
  const int rt0 = mi*16 + l4*4;
  // gate phase: wave computes tanh-rows mi*16.. and sigmoid-rows 64+mi*16..
  {
    float bt[4], bs[4];
#pragma unroll
    for (int r = 0; r < 4; ++r){ bt[r] = bh[rt0+r]; bs[r] = bh[64+rt0+r]; }
    const int rowt = mi*16 + l16, rows = 64 + mi*16 + l16;
    bf16x8 Ath[4], Atl[4], Ash[4], Asl[4];
#pragma unroll
    for (int kb = 0; kb < 4; ++kb){
      int ko = kb*32 + l4*8;
      Ath[kb] = *(const bf16x8*)(wgh + (size_t)rowt*128 + ko);
      Atl[kb] = *(const bf16x8*)(wgl + (size_t)rowt*128 + ko);
      Ash[kb] = *(const bf16x8*)(wgh + (size_t)rows*128 + ko);
      Asl[kb] = *(const bf16x8*)(wgl + (size_t)rows*128 + ko);
    }
#pragma unroll
    for (int nt = 0; nt < 2; ++nt){
      int col = (nh*2 + nt)*16 + l16;
      f32x4 at = {0.f,0.f,0.f,0.f}, as = {0.f,0.f,0.f,0.f};
#pragma unroll
      for (int kb = 0; kb < 4; ++kb){
        int ko = (kb*32 + l4*8) ^ (l16 << 3);
        bf16x8 bhv = *(const bf16x8*)&SHh[col*128 + ko];
        bf16x8 blv = *(const bf16x8*)&SHl[col*128 + ko];
        at = MFMA(Ath[kb], bhv, at);
        at = MFMA(Ath[kb], blv, at);
        at = MFMA(Atl[kb], bhv, at);
        as = MFMA(Ash[kb], bhv, as);
        as = MFMA(Ash[kb], blv, as);
        as = MFMA(Asl[kb], bhv, as);
      }
#pragma unroll
      for (int r = 0; r < 4; ++r){
        float av = at[r] + bt[r];
        float sv = as[r] + bs[r];
        float e2 = __expf(2.f*av);
        float tv = 1.f - 2.f/(e2 + 1.f);
        float sg = 1.f/(1.f + __expf(-sv));
        float g  = tv*sg;
        unsigned short gh, gl; split2(g, gh, gl);
        int kg = rt0 + r;
        int gi = col*64 + (kg ^ ((col & 7) << 3));
        SGh[gi] = (short)gh; SGl[gi] = (short)gl;
      }
    }
  }
  __syncthreads();

  // res phase: h_out = h_in + w_res@g + br   (wave: m-tile mi, n-half nh)
  {
    const int rowA = mi*16 + l16;
    bf16x8 Rh[2], Rl[2];
#pragma unroll
    for (int kb = 0; kb < 2; ++kb){
      int ko = kb*32 + l4*8;
      Rh[kb] = *(const bf16x8*)(wrh  + (size_t)rowA*64 + ko);
      Rl[kb] = *(const bf16x8*)(wrlo + (size_t)rowA*64 + ko);
    }
    float* ho = hout + (size_t)bb * 64 * T_;
#pragma unroll
    for (int nt = 0; nt < 2; ++nt){
      int col = (nh*2 + nt)*16 + l16;
      f32x4 acc = {0.f,0.f,0.f,0.f};
#pragma unroll
      for (int kb = 0; kb < 2; ++kb){
        int ko = (kb*32 + l4*8) ^ ((col & 7) << 3);
        bf16x8 bhv = *(const bf16x8*)&SGh[col*64 + ko];
        bf16x8 blv = *(const bf16x8*)&SGl[col*64 + ko];
        acc = MFMA(Rh[kb], bhv, acc);
        acc = MFMA(Rh[kb], blv, acc);
        acc = MFMA(Rl[kb], bhv, acc);
      }
      int t = t0 + col;
#pragma unroll
      for (int r = 0; r < 4; ++r){
        int rr = rt0 + r;
        size_t off = (size_t)rr*T_ + t;
        ho[off] = hb[off] + acc[r] + br[rr];
      }
    }
  }

  // skip phase: wave w owns rows w*32 .. w*32+31, all 4 n-tiles
  {
    const int m0 = w*32;
    const int r0 = m0 + l16, r1 = m0 + 16 + l16;
    bf16x8 S0h[2], S0l[2], S1h[2], S1l[2];
#pragma unroll
    for (int kb = 0; kb < 2; ++kb){
      int ko = kb*32 + l4*8;
      S0h[kb] = *(const bf16x8*)(wsh  + (size_t)r0*64 + ko);
      S0l[kb] = *(const bf16x8*)(wslo + (size_t)r0*64 + ko);
      S1h[kb] = *(const bf16x8*)(wsh  + (size_t)r1*64 + ko);
      S1l[kb] = *(const bf16x8*)(wslo + (size_t)r1*64 + ko);
    }
    float* sb = skip + (size_t)bb * 256 * T_;
#pragma unroll
    for (int nt = 0; nt < 4; ++nt){
      int col = nt*16 + l16;
      f32x4 a0 = {0.f,0.f,0.f,0.f}, a1 = {0.f,0.f,0.f,0.f};
#pragma unroll
      for (int kb = 0; kb < 2; ++kb){
        int ko = (kb*32 + l4*8) ^ ((col & 7) << 3);
        bf16x8 bhv = *(const bf16x8*)&SGh[col*64 + ko];
        bf16x8 blv = *(const bf16x8*)&SGl[col*64 + ko];
        a0 = MFMA(S0h[kb], bhv, a0);
        a0 = MFMA(S0h[kb], blv, a0);
        a0 = MFMA(S0l[kb], bhv, a0);
        a1 = MFMA(S1h[kb], bhv, a1);
        a1 = MFMA(S1h[kb], blv, a1);
        a1 = MFMA(S1l[kb], bhv, a1);
      }
      int t = t0 + col;
#pragma unroll
      for (int r = 0; r < 4; ++r){
        int s0 = m0 + l4*4 + r, s1 = s0 + 16;
        size_t o0 = (size_t)s0*T_ + t, o1 = (size_t)s1*T_ + t;
        float v0 = a0[r] + bsk[s0];
        float v1 = a1[r] + bsk[s1];
        if (!first){ v0 += sb[o0]; v1 += sb[o1]; }
        sb[o0] = v0; sb[o1] = v1;
      }
    }
  }
}

// ---------------- head-out: relu -> w_relu -> relu -> w_out -> softmax ----------------
__global__ __launch_bounds__(512) void k_head_out(
    float* __restrict__ io,
    const short* __restrict__ wrlh, const short* __restrict__ wrll,
    const float* __restrict__ brl,
    const short* __restrict__ woh, const short* __restrict__ wol,
    const float* __restrict__ bo)
{
  __shared__ short S1h[64*256], S1l[64*256];
  __shared__ float smax[8][64], ssum[8][64];
  const int tid = threadIdx.x;
  const int bb = blockIdx.x / NBT;
  const int t0 = (blockIdx.x % NBT) * 64;
  const int lane = tid & 63, w = tid >> 6;
  const int l16 = lane & 15, l4 = lane >> 4;

  float* iob = io + (size_t)bb * 256 * T_;
  // stage relu(skip) -> S1
  {
    int col = lane;
    int t = t0 + col;
#pragma unroll
    for (int p = 0; p < 16; ++p){
      int k0 = w*32 + p*2;
      float v0 = fmaxf(iob[(size_t)k0*T_ + t], 0.f);
      float v1 = fmaxf(iob[(size_t)(k0+1)*T_ + t], 0.f);
      unsigned short h0,l0,h1,l1; split2(v0,h0,l0); split2(v1,h1,l1);
      int idx = col*256 + (k0 ^ ((col & 15) << 3));
      ((unsigned int*)S1h)[idx>>1] = (unsigned)h0 | ((unsigned)h1 << 16);
      ((unsigned int*)S1l)[idx>>1] = (unsigned)l0 | ((unsigned)l1 << 16);
    }
  }
  __syncthreads();

  const int r0 = w*32 + l16, r1 = w*32 + 16 + l16;
  f32x4 acc0[4], acc1[4];
#pragma unroll
  for (int nt = 0; nt < 4; ++nt){ acc0[nt] = (f32x4){0.f,0.f,0.f,0.f}; acc1[nt] = (f32x4){0.f,0.f,0.f,0.f}; }
  // GEMM1: o = wrl @ s1
#pragma unroll
  for (int kb = 0; kb < 8; ++kb){
    int ko = kb*32 + l4*8;
    bf16x8 A0h = *(const bf16x8*)(wrlh + (size_t)r0*256 + ko);
    bf16x8 A0l = *(const bf16x8*)(wrll + (size_t)r0*256 + ko);
    bf16x8 A1h = *(const bf16x8*)(wrlh + (size_t)r1*256 + ko);
    bf16x8 A1l = *(const bf16x8*)(wrll + (size_t)r1*256 + ko);
#pragma unroll
    for (int nt = 0; nt < 4; ++nt){
      int c2 = nt*16 + l16;
      int kos = ko ^ (l16 << 3);
      bf16x8 bhv = *(const bf16x8*)&S1h[c2*256 + kos];
      bf16x8 blv = *(const bf16x8*)&S1l[c2*256 + kos];
      acc0[nt] = MFMA(A0h, bhv, acc0[nt]);
      acc0[nt] = MFMA(A0h, blv, acc0[nt]);
      acc0[nt] = MFMA(A0l, bhv, acc0[nt]);
      acc1[nt] = MFMA(A1h, bhv, acc1[nt]);
      acc1[nt] = MFMA(A1h, blv, acc1[nt]);
      acc1[nt] = MFMA(A1l, bhv, acc1[nt]);
    }
  }
  __syncthreads();
  // relu + write back into S1
#pragma unroll
  for (int nt = 0; nt < 4; ++nt){
    int c2 = nt*16 + l16;
#pragma unroll
    for (int r = 0; r < 4; ++r){
      int rr0 = w*32 + l4*4 + r, rr1 = rr0 + 16;
      float v0 = fmaxf(acc0[nt][r] + brl[rr0], 0.f);
      float v1 = fmaxf(acc1[nt][r] + brl[rr1], 0.f);
      unsigned short h0,l0,h1,l1; split2(v0,h0,l0); split2(v1,h1,l1);
      int i0 = c2*256 + (rr0 ^ (l16 << 3));
      int i1 = c2*256 + (rr1 ^ (l16 << 3));
      S1h[i0] = (short)h0; S1l[i0] = (short)l0;
      S1h[i1] = (short)h1; S1l[i1] = (short)l1;
    }
  }
  __syncthreads();
  // GEMM2: logits
#pragma unroll
  for (int nt = 0; nt < 4; ++nt){ acc0[nt] = (f32x4){0.f,0.f,0.f,0.f}; acc1[nt] = (f32x4){0.f,0.f,0.f,0.f}; }
#pragma unroll
  for (int kb = 0; kb < 8; ++kb){
    int ko = kb*32 + l4*8;
    bf16x8 A0h = *(const bf16x8*)(woh + (size_t)r0*256 + ko);
    bf16x8 A0l = *(const bf16x8*)(wol + (size_t)r0*256 + ko);
    bf16x8 A1h = *(const bf16x8*)(woh + (size_t)r1*256 + ko);
    bf16x8 A1l = *(const bf16x8*)(wol + (size_t)r1*256 + ko);
#pragma unroll
    for (int nt = 0; nt < 4; ++nt){
      int c2 = nt*16 + l16;
      int kos = ko ^ (l16 << 3);
      bf16x8 bhv = *(const bf16x8*)&S1h[c2*256 + kos];
      bf16x8 blv = *(const bf16x8*)&S1l[c2*256 + kos];
      acc0[nt] = MFMA(A0h, bhv, acc0[nt]);
      acc0[nt] = MFMA(A0h, blv, acc0[nt]);
      acc0[nt] = MFMA(A0l, bhv, acc0[nt]);
      acc1[nt] = MFMA(A1h, bhv, acc1[nt]);
      acc1[nt] = MFMA(A1h, blv, acc1[nt]);
      acc1[nt] = MFMA(A1l, bhv, acc1[nt]);
    }
  }
  float bo0[4], bo1[4];
#pragma unroll
  for (int r = 0; r < 4; ++r){ bo0[r] = bo[w*32 + l4*4 + r]; bo1[r] = bo[w*32 + 16 + l4*4 + r]; }
  // per-column max
#pragma unroll
  for (int nt = 0; nt < 4; ++nt){
    float m = -1e30f;
#pragma unroll
    for (int r = 0; r < 4; ++r){
      acc0[nt][r] += bo0[r];
      acc1[nt][r] += bo1[r];
      m = fmaxf(m, fmaxf(acc0[nt][r], acc1[nt][r]));
    }
    m = fmaxf(m, __shfl_xor(m, 16, 64));
    m = fmaxf(m, __shfl_xor(m, 32, 64));
    smax[w][nt*16 + l16] = m;
  }
  __syncthreads();
#pragma unroll
  for (int nt = 0; nt < 4; ++nt){
    float m = smax[0][nt*16 + l16];
#pragma unroll
    for (int ww = 1; ww < 8; ++ww) m = fmaxf(m, smax[ww][nt*16 + l16]);
    float s = 0.f;
#pragma unroll
    for (int r = 0; r < 4; ++r){
      acc0[nt][r] = __expf(acc0[nt][r] - m); s += acc0[nt][r];
      acc1[nt][r] = __expf(acc1[nt][r] - m); s += acc1[nt][r];
    }
    s += __shfl_xor(s, 16, 64);
    s += __shfl_xor(s, 32, 64);
    ssum[w][nt*16 + l16] = s;
  }
  __syncthreads();
#pragma unroll
  for (int nt = 0; nt < 4; ++nt){
    float S = 0.f;
#pragma unroll
    for (int ww = 0; ww < 8; ++ww) S += ssum[ww][nt*16 + l16];
    float inv = 1.f / S;
    int t = t0 + nt*16 + l16;
#pragma unroll
    for (int r = 0; r < 4; ++r){
      iob[(size_t)(w*32 + l4*4 + r)*T_ + t] = acc0[nt][r]*inv;
      iob[(size_t)(w*32 + 16 + l4*4 + r)*T_ + t] = acc1[nt][r]*inv;
    }
  }
}

extern "C" void kernel_launch(void* const* d_in, const int* in_sizes, int n_in,
                              void* d_out, int out_size, void* d_ws, size_t ws_size,
                              hipStream_t stream) {
  const float* x       = (const float*)d_in[0];
  const float* w_pre0  = (const float*)d_in[1];
  const float* b_pre0  = (const float*)d_in[2];
  const float* w_dil_p = (const float*)d_in[3];
  const float* w_dil_c = (const float*)d_in[4];
  const float* bias_h  = (const float*)d_in[5];
  const float* w_res   = (const float*)d_in[6];
  const float* b_res   = (const float*)d_in[7];
  const float* w_skip  = (const float*)d_in[8];
  const float* b_skip  = (const float*)d_in[9];
  const float* w_relu  = (const float*)d_in[10];
  const float* b_relu  = (const float*)d_in[11];
  const float* w_out   = (const float*)d_in[12];
  const float* b_out   = (const float*)d_in[13];

  float* out = (float*)d_out;              // skip accumulator, then softmax out
  float* hA = (float*)d_ws;
  float* hB = hA + (size_t)B_ * 64 * T_;
  short* p   = (short*)(hB + (size_t)B_ * 64 * T_);
  short* WPh = p; p += 16384;  short* WPl = p; p += 16384;
  short* WGh = p; p += 327680; short* WGl = p; p += 327680;
  short* WRh = p; p += 81920;  short* WRl = p; p += 81920;
  short* WSh = p; p += 327680; short* WSl = p; p += 327680;
  short* WLh = p; p += 65536;  short* WLl = p; p += 65536;
  short* WOh = p; p += 65536;  short* WOl = p; p += 65536;

  // weight split prep
  k_split<<<64, 256, 0, stream>>>(w_pre0, WPh, WPl, 16384);
  k_split_gate<<<1280, 256, 0, stream>>>(w_dil_p, w_dil_c, WGh, WGl);
  k_split<<<320, 256, 0, stream>>>(w_res, WRh, WRl, 81920);
  k_split<<<1280, 256, 0, stream>>>(w_skip, WSh, WSl, 327680);
  k_split<<<256, 256, 0, stream>>>(w_relu, WLh, WLl, 65536);
  k_split<<<256, 256, 0, stream>>>(w_out, WOh, WOl, 65536);

  k_head_in<<<B_ * NBT, 512, 0, stream>>>(x, WPh, WPl, b_pre0, hA);

  const float* hin = hA;
  float* houtp = hB;
  for (int l = 0; l < 20; ++l) {
    int d = 1 << (l % 10);
    k_layer<<<B_ * NBT, 512, 0, stream>>>(
        hin, houtp, out,
        WGh + (size_t)l*16384, WGl + (size_t)l*16384,
        WRh + (size_t)l*4096,  WRl + (size_t)l*4096,
        WSh + (size_t)l*16384, WSl + (size_t)l*16384,
        bias_h + (size_t)l*128, b_res + (size_t)l*64, b_skip + (size_t)l*256,
        d, l == 0 ? 1 : 0);
    const float* tmp = hin;
    hin = houtp;
    houtp = (float*)tmp;
  }

  k_head_out<<<B_ * NBT, 512, 0, stream>>>(out, WLh, WLl, b_relu, WOh, WOl, b_out);
}

// Round 5
// 1875.120 us; speedup vs baseline: 5.4374x; 1.2369x over previous
//
#include <hip/hip_runtime.h>
#include <math.h>

#define B_ 8
#define T_ 16000
#define NBT 250          // time-blocks of 64 cols

typedef __attribute__((ext_vector_type(8))) short bf16x8;
typedef __attribute__((ext_vector_type(4))) float f32x4;

__device__ __forceinline__ unsigned short f2bf(float f){
  unsigned u = __float_as_uint(f);
  u += 0x7fffu + ((u >> 16) & 1u);          // RNE to bf16
  return (unsigned short)(u >> 16);
}
__device__ __forceinline__ float bf2f(unsigned short s){
  return __uint_as_float(((unsigned)s) << 16);
}
__device__ __forceinline__ void split2(float v, unsigned short& hi, unsigned short& lo){
  hi = f2bf(v);
  lo = f2bf(v - bf2f(hi));
}

#define MFMA(a,b,c) __builtin_amdgcn_mfma_f32_16x16x32_bf16((a),(b),(c),0,0,0)

// ---------------- weight split prep ----------------
__global__ void k_split(const float* __restrict__ src, short* __restrict__ hi,
                        short* __restrict__ lo, int n){
  int idx = blockIdx.x * 256 + threadIdx.x;
  if (idx < n){
    unsigned short h, l; split2(src[idx], h, l);
    hi[idx] = (short)h; lo[idx] = (short)l;
  }
}
// gate weights: Wg[l][row][k] : k<64 -> wdp[l][row][k], else wdc[l][row][k-64]
__global__ void k_split_gate(const float* __restrict__ wdp, const float* __restrict__ wdc,
                             short* __restrict__ hi, short* __restrict__ lo){
  int idx = blockIdx.x * 256 + threadIdx.x;
  if (idx < 20*128*128){
    int l   = idx >> 14;
    int rem = idx & 16383;
    int row = rem >> 7;
    int k   = rem & 127;
    float v = (k < 64) ? wdp[(l*128 + row)*64 + k] : wdc[(l*128 + row)*64 + (k-64)];
    unsigned short h, lo16; split2(v, h, lo16);
    hi[idx] = (short)h; lo[idx] = (short)lo16;
  }
}
// bsum[s] = sum_l b_skip[l][s]
__global__ void k_bsum(const float* __restrict__ bsk, float* __restrict__ bsum){
  int s = threadIdx.x;
  if (s < 256){
    float a = 0.f;
#pragma unroll
    for (int l = 0; l < 20; ++l) a += bsk[l*256 + s];
    bsum[s] = a;
  }
}

// ---------------- head-in: h = 2*(w_pre0 @ shift(x,1) + b) ----------------
__global__ __launch_bounds__(512) void k_head_in(
    const float* __restrict__ x, const short* __restrict__ wph,
    const short* __restrict__ wpl, const float* __restrict__ bias,
    float* __restrict__ h)
{
  __shared__ short SXh[64*256], SXl[64*256];
  const int tid = threadIdx.x;
  const int bb = blockIdx.x / NBT;
  const int t0 = (blockIdx.x % NBT) * 64;
  const int lane = tid & 63, w = tid >> 6;
  const int l16 = lane & 15, l4 = lane >> 4;

  const float* xb = x + (size_t)bb * 256 * T_;
  {
    int col = lane;
    int t = t0 + col - 1;
#pragma unroll
    for (int p = 0; p < 16; ++p){
      int k0 = w*32 + p*2;
      float v0 = (t >= 0) ? xb[(size_t)k0*T_ + t] : 0.f;
      float v1 = (t >= 0) ? xb[(size_t)(k0+1)*T_ + t] : 0.f;
      unsigned short h0,l0,h1,l1; split2(v0,h0,l0); split2(v1,h1,l1);
      int idx = col*256 + (k0 ^ ((col & 15) << 3));
      ((unsigned int*)SXh)[idx>>1] = (unsigned)h0 | ((unsigned)h1 << 16);
      ((unsigned int*)SXl)[idx>>1] = (unsigned)l0 | ((unsigned)l1 << 16);
    }
  }
  __syncthreads();

  const int mi = w & 3, nh = w >> 2;
  const int rowA = mi*16 + l16;
  bf16x8 Ah[8], Al[8];
#pragma unroll
  for (int kb = 0; kb < 8; ++kb){
    int ko = kb*32 + l4*8;
    Ah[kb] = *(const bf16x8*)(wph + (size_t)rowA*256 + ko);
    Al[kb] = *(const bf16x8*)(wpl + (size_t)rowA*256 + ko);
  }
  float* hb = h + (size_t)bb * 64 * T_;
#pragma unroll
  for (int nt = 0; nt < 2; ++nt){
    int col = (nh*2 + nt)*16 + l16;
    f32x4 acc = {0.f,0.f,0.f,0.f};
#pragma unroll
    for (int kb = 0; kb < 8; ++kb){
      int ko = (kb*32 + l4*8) ^ (l16 << 3);
      bf16x8 bhv = *(const bf16x8*)&SXh[col*256 + ko];
      bf16x8 blv = *(const bf16x8*)&SXl[col*256 + ko];
      acc = MFMA(Ah[kb], bhv, acc);
      acc = MFMA(Ah[kb], blv, acc);
      acc = MFMA(Al[kb], bhv, acc);
    }
    int t = t0 + col;
#pragma unroll
    for (int r = 0; r < 4; ++r){
      int rr = mi*16 + l4*4 + r;
      hb[(size_t)rr*T_ + t] = 2.f*(acc[r] + bias[rr]);
    }
  }
}

// ---------------- per-layer kernel, g-output variant (no skip RMW) ----------------
__global__ __launch_bounds__(512) void k_layer_g(
    const float* __restrict__ hin, float* __restrict__ hout,
    short* __restrict__ gout,     // [b][t][64] bf16
    const short* __restrict__ wgh, const short* __restrict__ wgl,
    const short* __restrict__ wrh, const short* __restrict__ wrlo,
    const float* __restrict__ bh, const float* __restrict__ br, int d)
{
  __shared__ short SHh[64*128], SHl[64*128];   // [col][k] k<64=h_pre, k>=64=h
  __shared__ short SGh[64*64],  SGl[64*64];    // [col][kg] g
  const int tid = threadIdx.x;
  const int bb = blockIdx.x / NBT;
  const int t0 = (blockIdx.x % NBT) * 64;
  const int lane = tid & 63, w = tid >> 6;
  const int l16 = lane & 15, l4 = lane >> 4;

  const float* hb = hin + (size_t)bb * 64 * T_;
  {
    int col = lane;
#pragma unroll
    for (int p = 0; p < 8; ++p){
      int k0 = w*16 + p*2;
      int hr0 = k0 & 63, hr1 = (k0+1) & 63;
      int t = t0 + col - ((k0 < 64) ? d : 0);
      float v0 = (t >= 0) ? hb[(size_t)hr0*T_ + t] : 0.f;
      float v1 = (t >= 0) ? hb[(size_t)hr1*T_ + t] : 0.f;
      unsigned short h0,l0,h1,l1; split2(v0,h0,l0); split2(v1,h1,l1);
      int idx = col*128 + (k0 ^ ((col & 15) << 3));
      ((unsigned int*)SHh)[idx>>1] = (unsigned)h0 | ((unsigned)h1 << 16);
      ((unsigned int*)SHl)[idx>>1] = (unsigned)l0 | ((unsigned)l1 << 16);
    }
  }
  __syncthreads();

  const int mi = w & 3, nh = w >> 2;
  const int rt0 = mi*16 + l4*4;
  // gate phase
  {
    float bt[4], bs[4];
#pragma unroll
    for (int r = 0; r < 4; ++r){ bt[r] = bh[rt0+r]; bs[r] = bh[64+rt0+r]; }
    const int rowt = mi*16 + l16, rows = 64 + mi*16 + l16;
    bf16x8 Ath[4], Atl[4], Ash[4], Asl[4];
#pragma unroll
    for (int kb = 0; kb < 4; ++kb){
      int ko = kb*32 + l4*8;
      Ath[kb] = *(const bf16x8*)(wgh + (size_t)rowt*128 + ko);
      Atl[kb] = *(const bf16x8*)(wgl + (size_t)rowt*128 + ko);
      Ash[kb] = *(const bf16x8*)(wgh + (size_t)rows*128 + ko);
      Asl[kb] = *(const bf16x8*)(wgl + (size_t)rows*128 + ko);
    }
#pragma unroll
    for (int nt = 0; nt < 2; ++nt){
      int col = (nh*2 + nt)*16 + l16;
      f32x4 at = {0.f,0.f,0.f,0.f}, as = {0.f,0.f,0.f,0.f};
#pragma unroll
      for (int kb = 0; kb < 4; ++kb){
        int ko = (kb*32 + l4*8) ^ (l16 << 3);
        bf16x8 bhv = *(const bf16x8*)&SHh[col*128 + ko];
        bf16x8 blv = *(const bf16x8*)&SHl[col*128 + ko];
        at = MFMA(Ath[kb], bhv, at);
        at = MFMA(Ath[kb], blv, at);
        at = MFMA(Atl[kb], bhv, at);
        as = MFMA(Ash[kb], bhv, as);
        as = MFMA(Ash[kb], blv, as);
        as = MFMA(Asl[kb], bhv, as);
      }
      unsigned short gh4[4], gl4[4];
#pragma unroll
      for (int r = 0; r < 4; ++r){
        float av = at[r] + bt[r];
        float sv = as[r] + bs[r];
        float e2 = __expf(2.f*av);
        float tv = 1.f - 2.f/(e2 + 1.f);
        float sg = 1.f/(1.f + __expf(-sv));
        float g  = tv*sg;
        split2(g, gh4[r], gl4[r]);
        int kg = rt0 + r;
        int gi = col*64 + (kg ^ ((col & 7) << 3));
        SGh[gi] = (short)gh4[r]; SGl[gi] = (short)gl4[r];
      }
      // global g write (bf16 hi only), layout [b][t][64ch]
      {
        int t = t0 + col;
        unsigned d0 = (unsigned)gh4[0] | ((unsigned)gh4[1] << 16);
        unsigned d1 = (unsigned)gh4[2] | ((unsigned)gh4[3] << 16);
        unsigned int* gp = (unsigned int*)(gout + (((size_t)bb*T_ + t)*64 + rt0));
        gp[0] = d0; gp[1] = d1;
      }
    }
  }
  __syncthreads();

  // res phase: h_out = h_in + w_res@g + br
  {
    const int rowA = mi*16 + l16;
    bf16x8 Rh[2], Rl[2];
#pragma unroll
    for (int kb = 0; kb < 2; ++kb){
      int ko = kb*32 + l4*8;
      Rh[kb] = *(const bf16x8*)(wrh  + (size_t)rowA*64 + ko);
      Rl[kb] = *(const bf16x8*)(wrlo + (size_t)rowA*64 + ko);
    }
    float* ho = hout + (size_t)bb * 64 * T_;
#pragma unroll
    for (int nt = 0; nt < 2; ++nt){
      int col = (nh*2 + nt)*16 + l16;
      f32x4 acc = {0.f,0.f,0.f,0.f};
#pragma unroll
      for (int kb = 0; kb < 2; ++kb){
        int ko = (kb*32 + l4*8) ^ ((col & 7) << 3);
        bf16x8 bhv = *(const bf16x8*)&SGh[col*64 + ko];
        bf16x8 blv = *(const bf16x8*)&SGl[col*64 + ko];
        acc = MFMA(Rh[kb], bhv, acc);
        acc = MFMA(Rh[kb], blv, acc);
        acc = MFMA(Rl[kb], bhv, acc);
      }
      int t = t0 + col;
#pragma unroll
      for (int r = 0; r < 4; ++r){
        int rr = rt0 + r;
        size_t off = (size_t)rr*T_ + t;
        ho[off] = hb[off] + acc[r] + br[rr];
      }
    }
  }
}

// ---------------- fused head: skip K=1280 GEMM -> relu -> GEMM1 -> relu -> GEMM2 -> softmax ----
__global__ __launch_bounds__(512) void k_head_fused(
    float* __restrict__ io,                     // softmax out
    const short* __restrict__ g,                // [l][b][t][64] bf16
    const short* __restrict__ wsk,              // bf16 [l][256][64]
    const float* __restrict__ bsum,             // [256]
    const short* __restrict__ wrlh, const short* __restrict__ wrll,
    const float* __restrict__ brl,
    const short* __restrict__ woh, const short* __restrict__ wol,
    const float* __restrict__ bo)
{
  __shared__ short S1h[64*256], S1l[64*256];
  __shared__ float smax[8][64], ssum[8][64];
  const int tid = threadIdx.x;
  const int bb = blockIdx.x / NBT;
  const int t0 = (blockIdx.x % NBT) * 64;
  const int lane = tid & 63, w = tid >> 6;
  const int l16 = lane & 15, l4 = lane >> 4;

  const int r0 = w*32 + l16, r1 = w*32 + 16 + l16;
  const int rtb0 = w*32 + l4*4, rtb1 = rtb0 + 16;

  f32x4 acc0[4], acc1[4];
#pragma unroll
  for (int nt = 0; nt < 4; ++nt){ acc0[nt] = (f32x4){0.f,0.f,0.f,0.f}; acc1[nt] = (f32x4){0.f,0.f,0.f,0.f}; }

  // ---- skip GEMM: K = 20 layers x 64 ch, single-bf16 ----
  for (int kb = 0; kb < 40; ++kb){
    int l20 = kb >> 1;
    int koW = (kb & 1)*32 + l4*8;
    bf16x8 A0 = *(const bf16x8*)(wsk + ((size_t)l20*256 + r0)*64 + koW);
    bf16x8 A1 = *(const bf16x8*)(wsk + ((size_t)l20*256 + r1)*64 + koW);
    const short* gB = g + (((size_t)l20*B_ + bb)*T_)*64;
#pragma unroll
    for (int nt = 0; nt < 4; ++nt){
      int t = t0 + nt*16 + l16;
      bf16x8 Bv = *(const bf16x8*)(gB + (size_t)t*64 + koW);
      acc0[nt] = MFMA(A0, Bv, acc0[nt]);
      acc1[nt] = MFMA(A1, Bv, acc1[nt]);
    }
  }

  // bias + relu -> S1 (hi/lo), packed dword writes
  {
    float bs0[4], bs1[4];
#pragma unroll
    for (int r = 0; r < 4; ++r){ bs0[r] = bsum[rtb0+r]; bs1[r] = bsum[rtb1+r]; }
#pragma unroll
    for (int nt = 0; nt < 4; ++nt){
      int c2 = nt*16 + l16;
      unsigned short h[4], l[4];
#pragma unroll
      for (int r = 0; r < 4; ++r){
        float v = fmaxf(acc0[nt][r] + bs0[r], 0.f);
        split2(v, h[r], l[r]);
      }
      int i0 = c2*256 + (rtb0 ^ (l16 << 3));
      ((unsigned int*)&S1h[i0])[0] = (unsigned)h[0] | ((unsigned)h[1] << 16);
      ((unsigned int*)&S1h[i0])[1] = (unsigned)h[2] | ((unsigned)h[3] << 16);
      ((unsigned int*)&S1l[i0])[0] = (unsigned)l[0] | ((unsigned)l[1] << 16);
      ((unsigned int*)&S1l[i0])[1] = (unsigned)l[2] | ((unsigned)l[3] << 16);
#pragma unroll
      for (int r = 0; r < 4; ++r){
        float v = fmaxf(acc1[nt][r] + bs1[r], 0.f);
        split2(v, h[r], l[r]);
      }
      int i1 = c2*256 + (rtb1 ^ (l16 << 3));
      ((unsigned int*)&S1h[i1])[0] = (unsigned)h[0] | ((unsigned)h[1] << 16);
      ((unsigned int*)&S1h[i1])[1] = (unsigned)h[2] | ((unsigned)h[3] << 16);
      ((unsigned int*)&S1l[i1])[0] = (unsigned)l[0] | ((unsigned)l[1] << 16);
      ((unsigned int*)&S1l[i1])[1] = (unsigned)l[2] | ((unsigned)l[3] << 16);
    }
  }
  __syncthreads();

  // GEMM1: o = wrl @ s1 (hi/lo x hi/lo 3-MFMA)
#pragma unroll
  for (int nt = 0; nt < 4; ++nt){ acc0[nt] = (f32x4){0.f,0.f,0.f,0.f}; acc1[nt] = (f32x4){0.f,0.f,0.f,0.f}; }
#pragma unroll
  for (int kb = 0; kb < 8; ++kb){
    int ko = kb*32 + l4*8;
    bf16x8 A0h = *(const bf16x8*)(wrlh + (size_t)r0*256 + ko);
    bf16x8 A0l = *(const bf16x8*)(wrll + (size_t)r0*256 + ko);
    bf16x8 A1h = *(const bf16x8*)(wrlh + (size_t)r1*256 + ko);
    bf16x8 A1l = *(const bf16x8*)(wrll + (size_t)r1*256 + ko);
#pragma unroll
    for (int nt = 0; nt < 4; ++nt){
      int c2 = nt*16 + l16;
      int kos = ko ^ (l16 << 3);
      bf16x8 bhv = *(const bf16x8*)&S1h[c2*256 + kos];
      bf16x8 blv = *(const bf16x8*)&S1l[c2*256 + kos];
      acc0[nt] = MFMA(A0h, bhv, acc0[nt]);
      acc0[nt] = MFMA(A0h, blv, acc0[nt]);
      acc0[nt] = MFMA(A0l, bhv, acc0[nt]);
      acc1[nt] = MFMA(A1h, bhv, acc1[nt]);
      acc1[nt] = MFMA(A1h, blv, acc1[nt]);
      acc1[nt] = MFMA(A1l, bhv, acc1[nt]);
    }
  }
  __syncthreads();
  // relu + repack into S1
  {
    float br0[4], br1[4];
#pragma unroll
    for (int r = 0; r < 4; ++r){ br0[r] = brl[rtb0+r]; br1[r] = brl[rtb1+r]; }
#pragma unroll
    for (int nt = 0; nt < 4; ++nt){
      int c2 = nt*16 + l16;
      unsigned short h[4], l[4];
#pragma unroll
      for (int r = 0; r < 4; ++r){
        float v = fmaxf(acc0[nt][r] + br0[r], 0.f);
        split2(v, h[r], l[r]);
      }
      int i0 = c2*256 + (rtb0 ^ (l16 << 3));
      ((unsigned int*)&S1h[i0])[0] = (unsigned)h[0] | ((unsigned)h[1] << 16);
      ((unsigned int*)&S1h[i0])[1] = (unsigned)h[2] | ((unsigned)h[3] << 16);
      ((unsigned int*)&S1l[i0])[0] = (unsigned)l[0] | ((unsigned)l[1] << 16);
      ((unsigned int*)&S1l[i0])[1] = (unsigned)l[2] | ((unsigned)l[3] << 16);
#pragma unroll
      for (int r = 0; r < 4; ++r){
        float v = fmaxf(acc1[nt][r] + br1[r], 0.f);
        split2(v, h[r], l[r]);
      }
      int i1 = c2*256 + (rtb1 ^ (l16 << 3));
      ((unsigned int*)&S1h[i1])[0] = (unsigned)h[0] | ((unsigned)h[1] << 16);
      ((unsigned int*)&S1h[i1])[1] = (unsigned)h[2] | ((unsigned)h[3] << 16);
      ((unsigned int*)&S1l[i1])[0] = (unsigned)l[0] | ((unsigned)l[1] << 16);
      ((unsigned int*)&S1l[i1])[1] = (unsigned)l[2] | ((unsigned)l[3] << 16);
    }
  }
  __syncthreads();

  // GEMM2: logits
#pragma unroll
  for (int nt = 0; nt < 4; ++nt){ acc0[nt] = (f32x4){0.f,0.f,0.f,0.f}; acc1[nt] = (f32x4){0.f,0.f,0.f,0.f}; }
#pragma unroll
  for (int kb = 0; kb < 8; ++kb){
    int ko = kb*32 + l4*8;
    bf16x8 A0h = *(const bf16x8*)(woh + (size_t)r0*256 + ko);
    bf16x8 A0l = *(const bf16x8*)(wol + (size_t)r0*256 + ko);
    bf16x8 A1h = *(const bf16x8*)(woh + (size_t)r1*256 + ko);
    bf16x8 A1l = *(const bf16x8*)(wol + (size_t)r1*256 + ko);
#pragma unroll
    for (int nt = 0; nt < 4; ++nt){
      int c2 = nt*16 + l16;
      int kos = ko ^ (l16 << 3);
      bf16x8 bhv = *(const bf16x8*)&S1h[c2*256 + kos];
      bf16x8 blv = *(const bf16x8*)&S1l[c2*256 + kos];
      acc0[nt] = MFMA(A0h, bhv, acc0[nt]);
      acc0[nt] = MFMA(A0h, blv, acc0[nt]);
      acc0[nt] = MFMA(A0l, bhv, acc0[nt]);
      acc1[nt] = MFMA(A1h, bhv, acc1[nt]);
      acc1[nt] = MFMA(A1h, blv, acc1[nt]);
      acc1[nt] = MFMA(A1l, bhv, acc1[nt]);
    }
  }
  float* iob = io + (size_t)bb * 256 * T_;
  float bo0[4], bo1[4];
#pragma unroll
  for (int r = 0; r < 4; ++r){ bo0[r] = bo[rtb0+r]; bo1[r] = bo[rtb1+r]; }
#pragma unroll
  for (int nt = 0; nt < 4; ++nt){
    float m = -1e30f;
#pragma unroll
    for (int r = 0; r < 4; ++r){
      acc0[nt][r] += bo0[r];
      acc1[nt][r] += bo1[r];
      m = fmaxf(m, fmaxf(acc0[nt][r], acc1[nt][r]));
    }
    m = fmaxf(m, __shfl_xor(m, 16, 64));
    m = fmaxf(m, __shfl_xor(m, 32, 64));
    smax[w][nt*16 + l16] = m;
  }
  __syncthreads();
#pragma unroll
  for (int nt = 0; nt < 4; ++nt){
    float m = smax[0][nt*16 + l16];
#pragma unroll
    for (int ww = 1; ww < 8; ++ww) m = fmaxf(m, smax[ww][nt*16 + l16]);
    float s = 0.f;
#pragma unroll
    for (int r = 0; r < 4; ++r){
      acc0[nt][r] = __expf(acc0[nt][r] - m); s += acc0[nt][r];
      acc1[nt][r] = __expf(acc1[nt][r] - m); s += acc1[nt][r];
    }
    s += __shfl_xor(s, 16, 64);
    s += __shfl_xor(s, 32, 64);
    ssum[w][nt*16 + l16] = s;
  }
  __syncthreads();
#pragma unroll
  for (int nt = 0; nt < 4; ++nt){
    float S = 0.f;
#pragma unroll
    for (int ww = 0; ww < 8; ++ww) S += ssum[ww][nt*16 + l16];
    float inv = 1.f / S;
    int t = t0 + nt*16 + l16;
#pragma unroll
    for (int r = 0; r < 4; ++r){
      iob[(size_t)(rtb0 + r)*T_ + t] = acc0[nt][r]*inv;
      iob[(size_t)(rtb1 + r)*T_ + t] = acc1[nt][r]*inv;
    }
  }
}

// =================== LEGACY PATH (R4, used if ws too small) ===================
__global__ __launch_bounds__(512) void k_layer(
    const float* __restrict__ hin, float* __restrict__ hout,
    float* __restrict__ skip,
    const short* __restrict__ wgh, const short* __restrict__ wgl,
    const short* __restrict__ wrh, const short* __restrict__ wrlo,
    const short* __restrict__ wsh, const short* __restrict__ wslo,
    const float* __restrict__ bh, const float* __restrict__ br,
    const float* __restrict__ bsk, int d, int first)
{
  __shared__ short SHh[64*128], SHl[64*128];
  __shared__ short SGh[64*64],  SGl[64*64];
  const int tid = threadIdx.x;
  const int bb = blockIdx.x / NBT;
  const int t0 = (blockIdx.x % NBT) * 64;
  const int lane = tid & 63, w = tid >> 6;
  const int l16 = lane & 15, l4 = lane >> 4;

  const float* hb = hin + (size_t)bb * 64 * T_;
  {
    int col = lane;
#pragma unroll
    for (int p = 0; p < 8; ++p){
      int k0 = w*16 + p*2;
      int hr0 = k0 & 63, hr1 = (k0+1) & 63;
      int t = t0 + col - ((k0 < 64) ? d : 0);
      float v0 = (t >= 0) ? hb[(size_t)hr0*T_ + t] : 0.f;
      float v1 = (t >= 0) ? hb[(size_t)hr1*T_ + t] : 0.f;
      unsigned short h0,l0,h1,l1; split2(v0,h0,l0); split2(v1,h1,l1);
      int idx = col*128 + (k0 ^ ((col & 15) << 3));
      ((unsigned int*)SHh)[idx>>1] = (unsigned)h0 | ((unsigned)h1 << 16);
      ((unsigned int*)SHl)[idx>>1] = (unsigned)l0 | ((unsigned)l1 << 16);
    }
  }
  __syncthreads();

  const int mi = w & 3, nh = w >> 2;
  const int rt0 = mi*16 + l4*4;
  {
    float bt[4], bs[4];
#pragma unroll
    for (int r = 0; r < 4; ++r){ bt[r] = bh[rt0+r]; bs[r] = bh[64+rt0+r]; }
    const int rowt = mi*16 + l16, rows = 64 + mi*16 + l16;
    bf16x8 Ath[4], Atl[4], Ash[4], Asl[4];
#pragma unroll
    for (int kb = 0; kb < 4; ++kb){
      int ko = kb*32 + l4*8;
      Ath[kb] = *(const bf16x8*)(wgh + (size_t)rowt*128 + ko);
      Atl[kb] = *(const bf16x8*)(wgl + (size_t)rowt*128 + ko);
      Ash[kb] = *(const bf16x8*)(wgh + (size_t)rows*128 + ko);
      Asl[kb] = *(const bf16x8*)(wgl + (size_t)rows*128 + ko);
    }
#pragma unroll
    for (int nt = 0; nt < 2; ++nt){
      int col = (nh*2 + nt)*16 + l16;
      f32x4 at = {0.f,0.f,0.f,0.f}, as = {0.f,0.f,0.f,0.f};
#pragma unroll
      for (int kb = 0; kb < 4; ++kb){
        int ko = (kb*32 + l4*8) ^ (l16 << 3);
        bf16x8 bhv = *(const bf16x8*)&SHh[col*128 + ko];
        bf16x8 blv = *(const bf16x8*)&SHl[col*128 + ko];
        at = MFMA(Ath[kb], bhv, at);
        at = MFMA(Ath[kb], blv, at);
        at = MFMA(Atl[kb], bhv, at);
        as = MFMA(Ash[kb], bhv, as);
        as = MFMA(Ash[kb], blv, as);
        as = MFMA(Asl[kb], bhv, as);
      }
#pragma unroll
      for (int r = 0; r < 4; ++r){
        float av = at[r] + bt[r];
        float sv = as[r] + bs[r];
        float e2 = __expf(2.f*av);
        float tv = 1.f - 2.f/(e2 + 1.f);
        float sg = 1.f/(1.f + __expf(-sv));
        float g  = tv*sg;
        unsigned short gh, gl; split2(g, gh, gl);
        int kg = rt0 + r;
        int gi = col*64 + (kg ^ ((col & 7) << 3));
        SGh[gi] = (short)gh; SGl[gi] = (short)gl;
      }
    }
  }
  __syncthreads();

  {
    const int rowA = mi*16 + l16;
    bf16x8 Rh[2], Rl[2];
#pragma unroll
    for (int kb = 0; kb < 2; ++kb){
      int ko = kb*32 + l4*8;
      Rh[kb] = *(const bf16x8*)(wrh  + (size_t)rowA*64 + ko);
      Rl[kb] = *(const bf16x8*)(wrlo + (size_t)rowA*64 + ko);
    }
    float* ho = hout + (size_t)bb * 64 * T_;
#pragma unroll
    for (int nt = 0; nt < 2; ++nt){
      int col = (nh*2 + nt)*16 + l16;
      f32x4 acc = {0.f,0.f,0.f,0.f};
#pragma unroll
      for (int kb = 0; kb < 2; ++kb){
        int ko = (kb*32 + l4*8) ^ ((col & 7) << 3);
        bf16x8 bhv = *(const bf16x8*)&SGh[col*64 + ko];
        bf16x8 blv = *(const bf16x8*)&SGl[col*64 + ko];
        acc = MFMA(Rh[kb], bhv, acc);
        acc = MFMA(Rh[kb], blv, acc);
        acc = MFMA(Rl[kb], bhv, acc);
      }
      int t = t0 + col;
#pragma unroll
      for (int r = 0; r < 4; ++r){
        int rr = rt0 + r;
        size_t off = (size_t)rr*T_ + t;
        ho[off] = hb[off] + acc[r] + br[rr];
      }
    }
  }

  {
    const int m0 = w*32;
    const int r0 = m0 + l16, r1 = m0 + 16 + l16;
    bf16x8 S0h[2], S0l[2], S1h[2], S1l[2];
#pragma unroll
    for (int kb = 0; kb < 2; ++kb){
      int ko = kb*32 + l4*8;
      S0h[kb] = *(const bf16x8*)(wsh  + (size_t)r0*64 + ko);
      S0l[kb] = *(const bf16x8*)(wslo + (size_t)r0*64 + ko);
      S1h[kb] = *(const bf16x8*)(wsh  + (size_t)r1*64 + ko);
      S1l[kb] = *(const bf16x8*)(wslo + (size_t)r1*64 + ko);
    }
    float* sb = skip + (size_t)bb * 256 * T_;
#pragma unroll
    for (int nt = 0; nt < 4; ++nt){
      int col = nt*16 + l16;
      f32x4 a0 = {0.f,0.f,0.f,0.f}, a1 = {0.f,0.f,0.f,0.f};
#pragma unroll
      for (int kb = 0; kb < 2; ++kb){
        int ko = (kb*32 + l4*8) ^ ((col & 7) << 3);
        bf16x8 bhv = *(const bf16x8*)&SGh[col*64 + ko];
        bf16x8 blv = *(const bf16x8*)&SGl[col*64 + ko];
        a0 = MFMA(S0h[kb], bhv, a0);
        a0 = MFMA(S0h[kb], blv, a0);
        a0 = MFMA(S0l[kb], bhv, a0);
        a1 = MFMA(S1h[kb], bhv, a1);
        a1 = MFMA(S1h[kb], blv, a1);
        a1 = MFMA(S1l[kb], bhv, a1);
      }
      int t = t0 + col;
#pragma unroll
      for (int r = 0; r < 4; ++r){
        int s0 = m0 + l4*4 + r, s1 = s0 + 16;
        size_t o0 = (size_t)s0*T_ + t, o1 = (size_t)s1*T_ + t;
        float v0 = a0[r] + bsk[s0];
        float v1 = a1[r] + bsk[s1];
        if (!first){ v0 += sb[o0]; v1 += sb[o1]; }
        sb[o0] = v0; sb[o1] = v1;
      }
    }
  }
}

__global__ __launch_bounds__(512) void k_head_out(
    float* __restrict__ io,
    const short* __restrict__ wrlh, const short* __restrict__ wrll,
    const float* __restrict__ brl,
    const short* __restrict__ woh, const short* __restrict__ wol,
    const float* __restrict__ bo)
{
  __shared__ short S1h[64*256], S1l[64*256];
  __shared__ float smax[8][64], ssum[8][64];
  const int tid = threadIdx.x;
  const int bb = blockIdx.x / NBT;
  const int t0 = (blockIdx.x % NBT) * 64;
  const int lane = tid & 63, w = tid >> 6;
  const int l16 = lane & 15, l4 = lane >> 4;

  float* iob = io + (size_t)bb * 256 * T_;
  {
    int col = lane;
    int t = t0 + col;
#pragma unroll
    for (int p = 0; p < 16; ++p){
      int k0 = w*32 + p*2;
      float v0 = fmaxf(iob[(size_t)k0*T_ + t], 0.f);
      float v1 = fmaxf(iob[(size_t)(k0+1)*T_ + t], 0.f);
      unsigned short h0,l0,h1,l1; split2(v0,h0,l0); split2(v1,h1,l1);
      int idx = col*256 + (k0 ^ ((col & 15) << 3));
      ((unsigned int*)S1h)[idx>>1] = (unsigned)h0 | ((unsigned)h1 << 16);
      ((unsigned int*)S1l)[idx>>1] = (unsigned)l0 | ((unsigned)l1 << 16);
    }
  }
  __syncthreads();

  const int r0 = w*32 + l16, r1 = w*32 + 16 + l16;
  f32x4 acc0[4], acc1[4];
#pragma unroll
  for (int nt = 0; nt < 4; ++nt){ acc0[nt] = (f32x4){0.f,0.f,0.f,0.f}; acc1[nt] = (f32x4){0.f,0.f,0.f,0.f}; }
#pragma unroll
  for (int kb = 0; kb < 8; ++kb){
    int ko = kb*32 + l4*8;
    bf16x8 A0h = *(const bf16x8*)(wrlh + (size_t)r0*256 + ko);
    bf16x8 A0l = *(const bf16x8*)(wrll + (size_t)r0*256 + ko);
    bf16x8 A1h = *(const bf16x8*)(wrlh + (size_t)r1*256 + ko);
    bf16x8 A1l = *(const bf16x8*)(wrll + (size_t)r1*256 + ko);
#pragma unroll
    for (int nt = 0; nt < 4; ++nt){
      int c2 = nt*16 + l16;
      int kos = ko ^ (l16 << 3);
      bf16x8 bhv = *(const bf16x8*)&S1h[c2*256 + kos];
      bf16x8 blv = *(const bf16x8*)&S1l[c2*256 + kos];
      acc0[nt] = MFMA(A0h, bhv, acc0[nt]);
      acc0[nt] = MFMA(A0h, blv, acc0[nt]);
      acc0[nt] = MFMA(A0l, bhv, acc0[nt]);
      acc1[nt] = MFMA(A1h, bhv, acc1[nt]);
      acc1[nt] = MFMA(A1h, blv, acc1[nt]);
      acc1[nt] = MFMA(A1l, bhv, acc1[nt]);
    }
  }
  __syncthreads();
#pragma unroll
  for (int nt = 0; nt < 4; ++nt){
    int c2 = nt*16 + l16;
#pragma unroll
    for (int r = 0; r < 4; ++r){
      int rr0 = w*32 + l4*4 + r, rr1 = rr0 + 16;
      float v0 = fmaxf(acc0[nt][r] + brl[rr0], 0.f);
      float v1 = fmaxf(acc1[nt][r] + brl[rr1], 0.f);
      unsigned short h0,l0,h1,l1; split2(v0,h0,l0); split2(v1,h1,l1);
      int i0 = c2*256 + (rr0 ^ (l16 << 3));
      int i1 = c2*256 + (rr1 ^ (l16 << 3));
      S1h[i0] = (short)h0; S1l[i0] = (short)l0;
      S1h[i1] = (short)h1; S1l[i1] = (short)l1;
    }
  }
  __syncthreads();
#pragma unroll
  for (int nt = 0; nt < 4; ++nt){ acc0[nt] = (f32x4){0.f,0.f,0.f,0.f}; acc1[nt] = (f32x4){0.f,0.f,0.f,0.f}; }
#pragma unroll
  for (int kb = 0; kb < 8; ++kb){
    int ko = kb*32 + l4*8;
    bf16x8 A0h = *(const bf16x8*)(woh + (size_t)r0*256 + ko);
    bf16x8 A0l = *(const bf16x8*)(wol + (size_t)r0*256 + ko);
    bf16x8 A1h = *(const bf16x8*)(woh + (size_t)r1*256 + ko);
    bf16x8 A1l = *(const bf16x8*)(wol + (size_t)r1*256 + ko);
#pragma unroll
    for (int nt = 0; nt < 4; ++nt){
      int c2 = nt*16 + l16;
      int kos = ko ^ (l16 << 3);
      bf16x8 bhv = *(const bf16x8*)&S1h[c2*256 + kos];
      bf16x8 blv = *(const bf16x8*)&S1l[c2*256 + kos];
      acc0[nt] = MFMA(A0h, bhv, acc0[nt]);
      acc0[nt] = MFMA(A0h, blv, acc0[nt]);
      acc0[nt] = MFMA(A0l, bhv, acc0[nt]);
      acc1[nt] = MFMA(A1h, bhv, acc1[nt]);
      acc1[nt] = MFMA(A1h, blv, acc1[nt]);
      acc1[nt] = MFMA(A1l, bhv, acc1[nt]);
    }
  }
  float bo0[4], bo1[4];
#pragma unroll
  for (int r = 0; r < 4; ++r){ bo0[r] = bo[w*32 + l4*4 + r]; bo1[r] = bo[w*32 + 16 + l4*4 + r]; }
#pragma unroll
  for (int nt = 0; nt < 4; ++nt){
    float m = -1e30f;
#pragma unroll
    for (int r = 0; r < 4; ++r){
      acc0[nt][r] += bo0[r];
      acc1[nt][r] += bo1[r];
      m = fmaxf(m, fmaxf(acc0[nt][r], acc1[nt][r]));
    }
    m = fmaxf(m, __shfl_xor(m, 16, 64));
    m = fmaxf(m, __shfl_xor(m, 32, 64));
    smax[w][nt*16 + l16] = m;
  }
  __syncthreads();
#pragma unroll
  for (int nt = 0; nt < 4; ++nt){
    float m = smax[0][nt*16 + l16];
#pragma unroll
    for (int ww = 1; ww < 8; ++ww) m = fmaxf(m, smax[ww][nt*16 + l16]);
    float s = 0.f;
#pragma unroll
    for (int r = 0; r < 4; ++r){
      acc0[nt][r] = __expf(acc0[nt][r] - m); s += acc0[nt][r];
      acc1[nt][r] = __expf(acc1[nt][r] - m); s += acc1[nt][r];
    }
    s += __shfl_xor(s, 16, 64);
    s += __shfl_xor(s, 32, 64);
    ssum[w][nt*16 + l16] = s;
  }
  __syncthreads();
#pragma unroll
  for (int nt = 0; nt < 4; ++nt){
    float S = 0.f;
#pragma unroll
    for (int ww = 0; ww < 8; ++ww) S += ssum[ww][nt*16 + l16];
    float inv = 1.f / S;
    int t = t0 + nt*16 + l16;
#pragma unroll
    for (int r = 0; r < 4; ++r){
      iob[(size_t)(w*32 + l4*4 + r)*T_ + t] = acc0[nt][r]*inv;
      iob[(size_t)(w*32 + 16 + l4*4 + r)*T_ + t] = acc1[nt][r]*inv;
    }
  }
}

extern "C" void kernel_launch(void* const* d_in, const int* in_sizes, int n_in,
                              void* d_out, int out_size, void* d_ws, size_t ws_size,
                              hipStream_t stream) {
  const float* x       = (const float*)d_in[0];
  const float* w_pre0  = (const float*)d_in[1];
  const float* b_pre0  = (const float*)d_in[2];
  const float* w_dil_p = (const float*)d_in[3];
  const float* w_dil_c = (const float*)d_in[4];
  const float* bias_h  = (const float*)d_in[5];
  const float* w_res   = (const float*)d_in[6];
  const float* b_res   = (const float*)d_in[7];
  const float* w_skip  = (const float*)d_in[8];
  const float* b_skip  = (const float*)d_in[9];
  const float* w_relu  = (const float*)d_in[10];
  const float* b_relu  = (const float*)d_in[11];
  const float* w_out   = (const float*)d_in[12];
  const float* b_out   = (const float*)d_in[13];

  float* out = (float*)d_out;
  float* hA = (float*)d_ws;
  float* hB = hA + (size_t)B_ * 64 * T_;
  float* bsum = hB + (size_t)B_ * 64 * T_;
  short* p   = (short*)(bsum + 256);
  short* WPh = p; p += 16384;  short* WPl = p; p += 16384;
  short* WGh = p; p += 327680; short* WGl = p; p += 327680;
  short* WRh = p; p += 81920;  short* WRl = p; p += 81920;
  short* WSh = p; p += 327680; short* WSl = p; p += 327680;
  short* WLh = p; p += 65536;  short* WLl = p; p += 65536;
  short* WOh = p; p += 65536;  short* WOl = p; p += 65536;
  short* GBUF = p;             // 20*8*16000*64 shorts = 327.68 MB

  const size_t G_SHORTS = (size_t)20 * B_ * T_ * 64;
  const size_t need_new = ((char*)(GBUF + G_SHORTS)) - ((char*)d_ws);
  const bool big = (ws_size >= need_new);

  // weight split prep (shared by both paths)
  k_split<<<64, 256, 0, stream>>>(w_pre0, WPh, WPl, 16384);
  k_split_gate<<<1280, 256, 0, stream>>>(w_dil_p, w_dil_c, WGh, WGl);
  k_split<<<320, 256, 0, stream>>>(w_res, WRh, WRl, 81920);
  k_split<<<1280, 256, 0, stream>>>(w_skip, WSh, WSl, 327680);
  k_split<<<256, 256, 0, stream>>>(w_relu, WLh, WLl, 65536);
  k_split<<<256, 256, 0, stream>>>(w_out, WOh, WOl, 65536);

  k_head_in<<<B_ * NBT, 512, 0, stream>>>(x, WPh, WPl, b_pre0, hA);

  if (big) {
    k_bsum<<<1, 256, 0, stream>>>(b_skip, bsum);
    const float* hin = hA;
    float* houtp = hB;
    for (int l = 0; l < 20; ++l) {
      int d = 1 << (l % 10);
      k_layer_g<<<B_ * NBT, 512, 0, stream>>>(
          hin, houtp,
          GBUF + (size_t)l * B_ * T_ * 64,
          WGh + (size_t)l*16384, WGl + (size_t)l*16384,
          WRh + (size_t)l*4096,  WRl + (size_t)l*4096,
          bias_h + (size_t)l*128, b_res + (size_t)l*64, d);
      const float* tmp = hin;
      hin = houtp;
      houtp = (float*)tmp;
    }
    k_head_fused<<<B_ * NBT, 512, 0, stream>>>(
        out, GBUF, WSh, bsum, WLh, WLl, b_relu, WOh, WOl, b_out);
  } else {
    const float* hin = hA;
    float* houtp = hB;
    for (int l = 0; l < 20; ++l) {
      int d = 1 << (l % 10);
      k_layer<<<B_ * NBT, 512, 0, stream>>>(
          hin, houtp, out,
          WGh + (size_t)l*16384, WGl + (size_t)l*16384,
          WRh + (size_t)l*4096,  WRl + (size_t)l*4096,
          WSh + (size_t)l*16384, WSl + (size_t)l*16384,
          bias_h + (size_t)l*128, b_res + (size_t)l*64, b_skip + (size_t)l*256,
          d, l == 0 ? 1 : 0);
      const float* tmp = hin;
      hin = houtp;
      houtp = (float*)tmp;
    }
    k_head_out<<<B_ * NBT, 512, 0, stream>>>(out, WLh, WLl, b_relu, WOh, WOl, b_out);
  }
}

// Round 6
// 1666.689 us; speedup vs baseline: 6.1173x; 1.1251x over previous
//
#include <hip/hip_runtime.h>
#include <math.h>

#define B_ 8
#define T_ 16000
#define NBT 250          // time-blocks of 64 cols
#define HROWS 16512      // 512 guard rows + 16000
#define NLAY 20

typedef __attribute__((ext_vector_type(8))) short bf16x8;
typedef __attribute__((ext_vector_type(4))) float f32x4;
typedef __attribute__((ext_vector_type(4))) short sh4;

__device__ __forceinline__ unsigned short f2bf(float f){
  unsigned u = __float_as_uint(f);
  u += 0x7fffu + ((u >> 16) & 1u);          // RNE to bf16
  return (unsigned short)(u >> 16);
}
__device__ __forceinline__ float bf2f(unsigned short s){
  return __uint_as_float(((unsigned)s) << 16);
}
__device__ __forceinline__ void split2(float v, unsigned short& hi, unsigned short& lo){
  hi = f2bf(v);
  lo = f2bf(v - bf2f(hi));
}

#define MFMA(a,b,c) __builtin_amdgcn_mfma_f32_16x16x32_bf16((a),(b),(c),0,0,0)

// async global->LDS 16B per lane (dest = uniform base + lane*16, src per-lane)
__device__ __forceinline__ void gload16(const short* gsrc, short* ldst){
  __builtin_amdgcn_global_load_lds(
      (const __attribute__((address_space(1))) unsigned int*)gsrc,
      (__attribute__((address_space(3))) unsigned int*)ldst, 16, 0, 0);
}

// ---------------- prep kernels ----------------
__global__ void k_split(const float* __restrict__ src, short* __restrict__ hi,
                        short* __restrict__ lo, int n){
  int idx = blockIdx.x * 256 + threadIdx.x;
  if (idx < n){
    unsigned short h, l; split2(src[idx], h, l);
    hi[idx] = (short)h; lo[idx] = (short)l;
  }
}
__global__ void k_split_hi(const float* __restrict__ src, short* __restrict__ hi, int n){
  int idx = blockIdx.x * 256 + threadIdx.x;
  if (idx < n) hi[idx] = (short)f2bf(src[idx]);
}
// gate weights: Wg[l][row][k] : k<64 -> wdp[l][row][k], else wdc[l][row][k-64]
__global__ void k_split_gate(const float* __restrict__ wdp, const float* __restrict__ wdc,
                             short* __restrict__ hi, short* __restrict__ lo){
  int idx = blockIdx.x * 256 + threadIdx.x;
  if (idx < NLAY*128*128){
    int l   = idx >> 14;
    int rem = idx & 16383;
    int row = rem >> 7;
    int k   = rem & 127;
    float v = (k < 64) ? wdp[(l*128 + row)*64 + k] : wdc[(l*128 + row)*64 + (k-64)];
    unsigned short h, lo16; split2(v, h, lo16);
    hi[idx] = (short)h; lo[idx] = (short)lo16;
  }
}
__global__ void k_bsum(const float* __restrict__ bsk, float* __restrict__ bsum){
  int s = threadIdx.x;
  if (s < 256){
    float a = 0.f;
#pragma unroll
    for (int l = 0; l < NLAY; ++l) a += bsk[l*256 + s];
    bsum[s] = a;
  }
}
// zero the 512 guard rows of both h buffers (deterministic each call)
__global__ void k_zero_guard(short* __restrict__ hA, short* __restrict__ hB){
  int idx = blockIdx.x * 256 + threadIdx.x;
  if (idx < B_*512*128){
    int b = idx / (512*128);
    int rem = idx - b*(512*128);
    size_t off = (size_t)b*HROWS*128 + rem;
    hA[off] = 0; hB[off] = 0;
  }
}

// ---------------- head-in: h = 2*(w_pre0 @ shift(x,1) + b) -> swizzled bf16 hi/lo ----------------
__global__ __launch_bounds__(512) void k_head_in(
    const float* __restrict__ x, const short* __restrict__ wph,
    const short* __restrict__ wpl, const float* __restrict__ bias,
    short* __restrict__ h)
{
  __shared__ short SXh[64*256], SXl[64*256];
  const int tid = threadIdx.x;
  const int bb = blockIdx.x / NBT;
  const int t0 = (blockIdx.x % NBT) * 64;
  const int lane = tid & 63, w = tid >> 6;
  const int l16 = lane & 15, l4 = lane >> 4;

  const float* xb = x + (size_t)bb * 256 * T_;
  {
    int col = lane;
    int t = t0 + col - 1;
#pragma unroll
    for (int p = 0; p < 16; ++p){
      int k0 = w*32 + p*2;
      float v0 = (t >= 0) ? xb[(size_t)k0*T_ + t] : 0.f;
      float v1 = (t >= 0) ? xb[(size_t)(k0+1)*T_ + t] : 0.f;
      unsigned short h0,l0,h1,l1; split2(v0,h0,l0); split2(v1,h1,l1);
      int idx = col*256 + (k0 ^ ((col & 15) << 3));
      ((unsigned int*)SXh)[idx>>1] = (unsigned)h0 | ((unsigned)h1 << 16);
      ((unsigned int*)SXl)[idx>>1] = (unsigned)l0 | ((unsigned)l1 << 16);
    }
  }
  __syncthreads();

  const int mi = w & 3, nh = w >> 2;
  const int rowA = mi*16 + l16;
  const int rt0 = mi*16 + l4*4;
  bf16x8 Ah[8], Al[8];
#pragma unroll
  for (int kb = 0; kb < 8; ++kb){
    int ko = kb*32 + l4*8;
    Ah[kb] = *(const bf16x8*)(wph + (size_t)rowA*256 + ko);
    Al[kb] = *(const bf16x8*)(wpl + (size_t)rowA*256 + ko);
  }
  short* hb = h + ((size_t)bb*HROWS + 512)*128;
#pragma unroll
  for (int nt = 0; nt < 2; ++nt){
    int col = (nh*2 + nt)*16 + l16;
    f32x4 acc = {0.f,0.f,0.f,0.f};
#pragma unroll
    for (int kb = 0; kb < 8; ++kb){
      int ko = (kb*32 + l4*8) ^ (l16 << 3);
      bf16x8 bhv = *(const bf16x8*)&SXh[col*256 + ko];
      bf16x8 blv = *(const bf16x8*)&SXl[col*256 + ko];
      acc = MFMA(Ah[kb], bhv, acc);
      acc = MFMA(Ah[kb], blv, acc);
      acc = MFMA(Al[kb], bhv, acc);
    }
    int t = t0 + col;
    int key = t & 15;
    int c  = rt0 >> 3, sub = rt0 & 7;
    sh4 hv, lv;
#pragma unroll
    for (int r = 0; r < 4; ++r){
      float v = 2.f*(acc[r] + bias[rt0 + r]);
      unsigned short hh, ll; split2(v, hh, ll);
      hv[r] = (short)hh; lv[r] = (short)ll;
    }
    *(sh4*)&hb[(size_t)t*128 + ((c ^ key) << 3) + sub] = hv;
    *(sh4*)&hb[(size_t)t*128 + (((c + 8) ^ key) << 3) + sub] = lv;
  }
}

// ---------------- per-layer kernel: bf16 h in/out, async LDS staging ----------------
__global__ __launch_bounds__(512) void k_layer2(
    const short* __restrict__ hin, short* __restrict__ hout,
    short* __restrict__ gout,     // [b][t][64] bf16 hi
    const short* __restrict__ wgh, const short* __restrict__ wgl,
    const short* __restrict__ wrh, const short* __restrict__ wrlo,
    const float* __restrict__ bh, const float* __restrict__ br, int d)
{
  __shared__ short SH[64*128];     // cur h rows (hi|lo, swizzled as in global)
  __shared__ short SHP[64*128];    // shifted h rows
  __shared__ short SGh[64*64], SGl[64*64];
  const int tid = threadIdx.x;
  const int bb = blockIdx.x / NBT;
  const int t0 = (blockIdx.x % NBT) * 64;
  const int lane = tid & 63, w = tid >> 6;
  const int l16 = lane & 15, l4 = lane >> 4;

  const short* hb = hin + ((size_t)bb*HROWS + 512)*128;
  // async stage: wave w covers col quads 2w, 2w+1 for both tiles
  {
#pragma unroll
    for (int i = 0; i < 2; ++i){
      int colb = (w*2 + i)*4;
      const short* s1 = hb + (size_t)(t0 + colb + (lane>>4))*128 + (lane&15)*8;
      gload16(s1, &SH[colb*128]);
      const short* s2 = hb + (size_t)(t0 - d + colb + (lane>>4))*128 + (lane&15)*8;
      gload16(s2, &SHP[colb*128]);
    }
  }

  const int mi = w & 3, nh = w >> 2;
  const int rt0 = mi*16 + l4*4;
  // preload gate A fragments (overlaps staging drain)
  const int rowt = mi*16 + l16, rows = 64 + mi*16 + l16;
  bf16x8 Ath[4], Atl[4], Ash[4], Asl[4];
#pragma unroll
  for (int kb = 0; kb < 4; ++kb){
    int ko = kb*32 + l4*8;
    Ath[kb] = *(const bf16x8*)(wgh + (size_t)rowt*128 + ko);
    Atl[kb] = *(const bf16x8*)(wgl + (size_t)rowt*128 + ko);
    Ash[kb] = *(const bf16x8*)(wgh + (size_t)rows*128 + ko);
    Asl[kb] = *(const bf16x8*)(wgl + (size_t)rows*128 + ko);
  }
  float bt[4], bs[4];
#pragma unroll
  for (int r = 0; r < 4; ++r){ bt[r] = bh[rt0+r]; bs[r] = bh[64+rt0+r]; }
  __syncthreads();   // drains global_load_lds (vmcnt0) + barrier

  // gate phase
#pragma unroll
  for (int nt = 0; nt < 2; ++nt){
    int col = (nh*2 + nt)*16 + l16;
    int keyC = col & 15;
    int keyP = (col - d) & 15;
    f32x4 at = {0.f,0.f,0.f,0.f}, as = {0.f,0.f,0.f,0.f};
#pragma unroll
    for (int kb = 0; kb < 4; ++kb){
      const short* tile = (kb < 2) ? SHP : SH;
      int key = (kb < 2) ? keyP : keyC;
      int cb = (kb & 1)*4 + l4;
      bf16x8 bhv = *(const bf16x8*)&tile[col*128 + ((cb ^ key) << 3)];
      bf16x8 blv = *(const bf16x8*)&tile[col*128 + (((cb + 8) ^ key) << 3)];
      at = MFMA(Ath[kb], bhv, at);
      at = MFMA(Ath[kb], blv, at);
      at = MFMA(Atl[kb], bhv, at);
      as = MFMA(Ash[kb], bhv, as);
      as = MFMA(Ash[kb], blv, as);
      as = MFMA(Asl[kb], bhv, as);
    }
    unsigned short gh4[4], gl4[4];
#pragma unroll
    for (int r = 0; r < 4; ++r){
      float av = at[r] + bt[r];
      float sv = as[r] + bs[r];
      float e2 = __expf(2.f*av);
      float tv = 1.f - 2.f/(e2 + 1.f);
      float sg = 1.f/(1.f + __expf(-sv));
      float g  = tv*sg;
      split2(g, gh4[r], gl4[r]);
      int gi = col*64 + ((rt0 + r) ^ ((col & 7) << 3));
      SGh[gi] = (short)gh4[r]; SGl[gi] = (short)gl4[r];
    }
    {   // g hi to global, [b][t][64]
      int t = t0 + col;
      sh4 gv; gv[0]=(short)gh4[0]; gv[1]=(short)gh4[1]; gv[2]=(short)gh4[2]; gv[3]=(short)gh4[3];
      *(sh4*)(gout + ((size_t)bb*T_ + t)*64 + rt0) = gv;
    }
  }
  __syncthreads();

  // res phase: h_out = h_in + w_res@g + br
  {
    const int rowA = mi*16 + l16;
    bf16x8 Rh[2], Rl[2];
#pragma unroll
    for (int kb = 0; kb < 2; ++kb){
      int ko = kb*32 + l4*8;
      Rh[kb] = *(const bf16x8*)(wrh  + (size_t)rowA*64 + ko);
      Rl[kb] = *(const bf16x8*)(wrlo + (size_t)rowA*64 + ko);
    }
    short* ho = hout + ((size_t)bb*HROWS + 512)*128;
    const int cH = rt0 >> 3, sub = rt0 & 7;
#pragma unroll
    for (int nt = 0; nt < 2; ++nt){
      int col = (nh*2 + nt)*16 + l16;
      int keyC = col & 15;
      f32x4 acc = {0.f,0.f,0.f,0.f};
#pragma unroll
      for (int kb = 0; kb < 2; ++kb){
        int ko = (kb*32 + l4*8) ^ ((col & 7) << 3);
        bf16x8 bhv = *(const bf16x8*)&SGh[col*64 + ko];
        bf16x8 blv = *(const bf16x8*)&SGl[col*64 + ko];
        acc = MFMA(Rh[kb], bhv, acc);
        acc = MFMA(Rh[kb], blv, acc);
        acc = MFMA(Rl[kb], bhv, acc);
      }
      sh4 hi4 = *(const sh4*)&SH[col*128 + ((cH ^ keyC) << 3) + sub];
      sh4 lo4 = *(const sh4*)&SH[col*128 + (((cH + 8) ^ keyC) << 3) + sub];
      int t = t0 + col;
      sh4 hv, lv;
#pragma unroll
      for (int r = 0; r < 4; ++r){
        float hin_f = bf2f((unsigned short)hi4[r]) + bf2f((unsigned short)lo4[r]);
        float v = hin_f + acc[r] + br[rt0 + r];
        unsigned short hh, ll; split2(v, hh, ll);
        hv[r] = (short)hh; lv[r] = (short)ll;
      }
      *(sh4*)&ho[(size_t)t*128 + ((cH ^ keyC) << 3) + sub] = hv;
      *(sh4*)&ho[(size_t)t*128 + (((cH + 8) ^ keyC) << 3) + sub] = lv;
    }
  }
}

// ---------------- fused head: skip K=1280 GEMM -> relu -> GEMM1 -> relu -> GEMM2 -> softmax ----
__global__ __launch_bounds__(512) void k_head_fused(
    float* __restrict__ io,
    const short* __restrict__ g,                // [l][b][t][64] bf16
    const short* __restrict__ wsk,              // bf16 [l][256][64]
    const float* __restrict__ bsum,
    const short* __restrict__ wrlh, const short* __restrict__ wrll,
    const float* __restrict__ brl,
    const short* __restrict__ woh, const short* __restrict__ wol,
    const float* __restrict__ bo)
{
  __shared__ short S1h[64*256], S1l[64*256];
  __shared__ float smax[8][64], ssum[8][64];
  const int tid = threadIdx.x;
  const int bb = blockIdx.x / NBT;
  const int t0 = (blockIdx.x % NBT) * 64;
  const int lane = tid & 63, w = tid >> 6;
  const int l16 = lane & 15, l4 = lane >> 4;

  const int r0 = w*32 + l16, r1 = w*32 + 16 + l16;
  const int rtb0 = w*32 + l4*4, rtb1 = rtb0 + 16;

  f32x4 acc0[4], acc1[4];
#pragma unroll
  for (int nt = 0; nt < 4; ++nt){ acc0[nt] = (f32x4){0.f,0.f,0.f,0.f}; acc1[nt] = (f32x4){0.f,0.f,0.f,0.f}; }

  // ---- skip GEMM, 2-deep register pipeline (static buffers only) ----
  auto LK = [&](int kb, bf16x8& A0v, bf16x8& A1v,
                bf16x8& B0, bf16x8& B1, bf16x8& B2, bf16x8& B3){
    int l20 = kb >> 1;
    int koW = (kb & 1)*32 + l4*8;
    A0v = *(const bf16x8*)(wsk + ((size_t)l20*256 + r0)*64 + koW);
    A1v = *(const bf16x8*)(wsk + ((size_t)l20*256 + r1)*64 + koW);
    const short* gB = g + (((size_t)l20*B_ + bb)*T_)*64 + koW;
    B0 = *(const bf16x8*)(gB + (size_t)(t0      + l16)*64);
    B1 = *(const bf16x8*)(gB + (size_t)(t0 + 16 + l16)*64);
    B2 = *(const bf16x8*)(gB + (size_t)(t0 + 32 + l16)*64);
    B3 = *(const bf16x8*)(gB + (size_t)(t0 + 48 + l16)*64);
  };
  bf16x8 A0a,A1a,Ba0,Ba1,Ba2,Ba3, A0b,A1b,Bb0,Bb1,Bb2,Bb3;
  LK(0, A0a,A1a,Ba0,Ba1,Ba2,Ba3);
  for (int kb = 0; kb < 40; kb += 2){
    LK(kb+1, A0b,A1b,Bb0,Bb1,Bb2,Bb3);
    acc0[0] = MFMA(A0a, Ba0, acc0[0]); acc1[0] = MFMA(A1a, Ba0, acc1[0]);
    acc0[1] = MFMA(A0a, Ba1, acc0[1]); acc1[1] = MFMA(A1a, Ba1, acc1[1]);
    acc0[2] = MFMA(A0a, Ba2, acc0[2]); acc1[2] = MFMA(A1a, Ba2, acc1[2]);
    acc0[3] = MFMA(A0a, Ba3, acc0[3]); acc1[3] = MFMA(A1a, Ba3, acc1[3]);
    if (kb + 2 < 40) LK(kb+2, A0a,A1a,Ba0,Ba1,Ba2,Ba3);
    acc0[0] = MFMA(A0b, Bb0, acc0[0]); acc1[0] = MFMA(A1b, Bb0, acc1[0]);
    acc0[1] = MFMA(A0b, Bb1, acc0[1]); acc1[1] = MFMA(A1b, Bb1, acc1[1]);
    acc0[2] = MFMA(A0b, Bb2, acc0[2]); acc1[2] = MFMA(A1b, Bb2, acc1[2]);
    acc0[3] = MFMA(A0b, Bb3, acc0[3]); acc1[3] = MFMA(A1b, Bb3, acc1[3]);
  }

  // bias + relu -> S1 (hi/lo), packed dword writes
  {
    float bs0[4], bs1[4];
#pragma unroll
    for (int r = 0; r < 4; ++r){ bs0[r] = bsum[rtb0+r]; bs1[r] = bsum[rtb1+r]; }
#pragma unroll
    for (int nt = 0; nt < 4; ++nt){
      int c2 = nt*16 + l16;
      unsigned short h[4], l[4];
#pragma unroll
      for (int r = 0; r < 4; ++r){
        float v = fmaxf(acc0[nt][r] + bs0[r], 0.f);
        split2(v, h[r], l[r]);
      }
      int i0 = c2*256 + (rtb0 ^ (l16 << 3));
      ((unsigned int*)&S1h[i0])[0] = (unsigned)h[0] | ((unsigned)h[1] << 16);
      ((unsigned int*)&S1h[i0])[1] = (unsigned)h[2] | ((unsigned)h[3] << 16);
      ((unsigned int*)&S1l[i0])[0] = (unsigned)l[0] | ((unsigned)l[1] << 16);
      ((unsigned int*)&S1l[i0])[1] = (unsigned)l[2] | ((unsigned)l[3] << 16);
#pragma unroll
      for (int r = 0; r < 4; ++r){
        float v = fmaxf(acc1[nt][r] + bs1[r], 0.f);
        split2(v, h[r], l[r]);
      }
      int i1 = c2*256 + (rtb1 ^ (l16 << 3));
      ((unsigned int*)&S1h[i1])[0] = (unsigned)h[0] | ((unsigned)h[1] << 16);
      ((unsigned int*)&S1h[i1])[1] = (unsigned)h[2] | ((unsigned)h[3] << 16);
      ((unsigned int*)&S1l[i1])[0] = (unsigned)l[0] | ((unsigned)l[1] << 16);
      ((unsigned int*)&S1l[i1])[1] = (unsigned)l[2] | ((unsigned)l[3] << 16);
    }
  }
  __syncthreads();

  // GEMM1
#pragma unroll
  for (int nt = 0; nt < 4; ++nt){ acc0[nt] = (f32x4){0.f,0.f,0.f,0.f}; acc1[nt] = (f32x4){0.f,0.f,0.f,0.f}; }
#pragma unroll
  for (int kb = 0; kb < 8; ++kb){
    int ko = kb*32 + l4*8;
    bf16x8 A0h = *(const bf16x8*)(wrlh + (size_t)r0*256 + ko);
    bf16x8 A0l = *(const bf16x8*)(wrll + (size_t)r0*256 + ko);
    bf16x8 A1h = *(const bf16x8*)(wrlh + (size_t)r1*256 + ko);
    bf16x8 A1l = *(const bf16x8*)(wrll + (size_t)r1*256 + ko);
#pragma unroll
    for (int nt = 0; nt < 4; ++nt){
      int c2 = nt*16 + l16;
      int kos = ko ^ (l16 << 3);
      bf16x8 bhv = *(const bf16x8*)&S1h[c2*256 + kos];
      bf16x8 blv = *(const bf16x8*)&S1l[c2*256 + kos];
      acc0[nt] = MFMA(A0h, bhv, acc0[nt]);
      acc0[nt] = MFMA(A0h, blv, acc0[nt]);
      acc0[nt] = MFMA(A0l, bhv, acc0[nt]);
      acc1[nt] = MFMA(A1h, bhv, acc1[nt]);
      acc1[nt] = MFMA(A1h, blv, acc1[nt]);
      acc1[nt] = MFMA(A1l, bhv, acc1[nt]);
    }
  }
  __syncthreads();
  // relu + repack into S1
  {
    float br0[4], br1[4];
#pragma unroll
    for (int r = 0; r < 4; ++r){ br0[r] = brl[rtb0+r]; br1[r] = brl[rtb1+r]; }
#pragma unroll
    for (int nt = 0; nt < 4; ++nt){
      int c2 = nt*16 + l16;
      unsigned short h[4], l[4];
#pragma unroll
      for (int r = 0; r < 4; ++r){
        float v = fmaxf(acc0[nt][r] + br0[r], 0.f);
        split2(v, h[r], l[r]);
      }
      int i0 = c2*256 + (rtb0 ^ (l16 << 3));
      ((unsigned int*)&S1h[i0])[0] = (unsigned)h[0] | ((unsigned)h[1] << 16);
      ((unsigned int*)&S1h[i0])[1] = (unsigned)h[2] | ((unsigned)h[3] << 16);
      ((unsigned int*)&S1l[i0])[0] = (unsigned)l[0] | ((unsigned)l[1] << 16);
      ((unsigned int*)&S1l[i0])[1] = (unsigned)l[2] | ((unsigned)l[3] << 16);
#pragma unroll
      for (int r = 0; r < 4; ++r){
        float v = fmaxf(acc1[nt][r] + br1[r], 0.f);
        split2(v, h[r], l[r]);
      }
      int i1 = c2*256 + (rtb1 ^ (l16 << 3));
      ((unsigned int*)&S1h[i1])[0] = (unsigned)h[0] | ((unsigned)h[1] << 16);
      ((unsigned int*)&S1h[i1])[1] = (unsigned)h[2] | ((unsigned)h[3] << 16);
      ((unsigned int*)&S1l[i1])[0] = (unsigned)l[0] | ((unsigned)l[1] << 16);
      ((unsigned int*)&S1l[i1])[1] = (unsigned)l[2] | ((unsigned)l[3] << 16);
    }
  }
  __syncthreads();

  // GEMM2: logits
#pragma unroll
  for (int nt = 0; nt < 4; ++nt){ acc0[nt] = (f32x4){0.f,0.f,0.f,0.f}; acc1[nt] = (f32x4){0.f,0.f,0.f,0.f}; }
#pragma unroll
  for (int kb = 0; kb < 8; ++kb){
    int ko = kb*32 + l4*8;
    bf16x8 A0h = *(const bf16x8*)(woh + (size_t)r0*256 + ko);
    bf16x8 A0l = *(const bf16x8*)(wol + (size_t)r0*256 + ko);
    bf16x8 A1h = *(const bf16x8*)(woh + (size_t)r1*256 + ko);
    bf16x8 A1l = *(const bf16x8*)(wol + (size_t)r1*256 + ko);
#pragma unroll
    for (int nt = 0; nt < 4; ++nt){
      int c2 = nt*16 + l16;
      int kos = ko ^ (l16 << 3);
      bf16x8 bhv = *(const bf16x8*)&S1h[c2*256 + kos];
      bf16x8 blv = *(const bf16x8*)&S1l[c2*256 + kos];
      acc0[nt] = MFMA(A0h, bhv, acc0[nt]);
      acc0[nt] = MFMA(A0h, blv, acc0[nt]);
      acc0[nt] = MFMA(A0l, bhv, acc0[nt]);
      acc1[nt] = MFMA(A1h, bhv, acc1[nt]);
      acc1[nt] = MFMA(A1h, blv, acc1[nt]);
      acc1[nt] = MFMA(A1l, bhv, acc1[nt]);
    }
  }
  float* iob = io + (size_t)bb * 256 * T_;
  float bo0[4], bo1[4];
#pragma unroll
  for (int r = 0; r < 4; ++r){ bo0[r] = bo[rtb0+r]; bo1[r] = bo[rtb1+r]; }
#pragma unroll
  for (int nt = 0; nt < 4; ++nt){
    float m = -1e30f;
#pragma unroll
    for (int r = 0; r < 4; ++r){
      acc0[nt][r] += bo0[r];
      acc1[nt][r] += bo1[r];
      m = fmaxf(m, fmaxf(acc0[nt][r], acc1[nt][r]));
    }
    m = fmaxf(m, __shfl_xor(m, 16, 64));
    m = fmaxf(m, __shfl_xor(m, 32, 64));
    smax[w][nt*16 + l16] = m;
  }
  __syncthreads();
#pragma unroll
  for (int nt = 0; nt < 4; ++nt){
    float m = smax[0][nt*16 + l16];
#pragma unroll
    for (int ww = 1; ww < 8; ++ww) m = fmaxf(m, smax[ww][nt*16 + l16]);
    float s = 0.f;
#pragma unroll
    for (int r = 0; r < 4; ++r){
      acc0[nt][r] = __expf(acc0[nt][r] - m); s += acc0[nt][r];
      acc1[nt][r] = __expf(acc1[nt][r] - m); s += acc1[nt][r];
    }
    s += __shfl_xor(s, 16, 64);
    s += __shfl_xor(s, 32, 64);
    ssum[w][nt*16 + l16] = s;
  }
  __syncthreads();
#pragma unroll
  for (int nt = 0; nt < 4; ++nt){
    float S = 0.f;
#pragma unroll
    for (int ww = 0; ww < 8; ++ww) S += ssum[ww][nt*16 + l16];
    float inv = 1.f / S;
    int t = t0 + nt*16 + l16;
#pragma unroll
    for (int r = 0; r < 4; ++r){
      iob[(size_t)(rtb0 + r)*T_ + t] = acc0[nt][r]*inv;
      iob[(size_t)(rtb1 + r)*T_ + t] = acc1[nt][r]*inv;
    }
  }
}

extern "C" void kernel_launch(void* const* d_in, const int* in_sizes, int n_in,
                              void* d_out, int out_size, void* d_ws, size_t ws_size,
                              hipStream_t stream) {
  const float* x       = (const float*)d_in[0];
  const float* w_pre0  = (const float*)d_in[1];
  const float* b_pre0  = (const float*)d_in[2];
  const float* w_dil_p = (const float*)d_in[3];
  const float* w_dil_c = (const float*)d_in[4];
  const float* bias_h  = (const float*)d_in[5];
  const float* w_res   = (const float*)d_in[6];
  const float* b_res   = (const float*)d_in[7];
  const float* w_skip  = (const float*)d_in[8];
  const float* b_skip  = (const float*)d_in[9];
  const float* w_relu  = (const float*)d_in[10];
  const float* b_relu  = (const float*)d_in[11];
  const float* w_out   = (const float*)d_in[12];
  const float* b_out   = (const float*)d_in[13];

  float* out = (float*)d_out;
  short* hA = (short*)d_ws;
  short* hB = hA + (size_t)B_ * HROWS * 128;
  float* bsum = (float*)(hB + (size_t)B_ * HROWS * 128);
  short* p   = (short*)(bsum + 256);
  short* WPh = p; p += 16384;  short* WPl = p; p += 16384;
  short* WGh = p; p += 327680; short* WGl = p; p += 327680;
  short* WRh = p; p += 81920;  short* WRl = p; p += 81920;
  short* WSh = p; p += 327680;
  short* WLh = p; p += 65536;  short* WLl = p; p += 65536;
  short* WOh = p; p += 65536;  short* WOl = p; p += 65536;
  short* GBUF = p;             // 20*8*16000*64 shorts = 327.68 MB

  // weight prep
  k_split<<<64, 256, 0, stream>>>(w_pre0, WPh, WPl, 16384);
  k_split_gate<<<1280, 256, 0, stream>>>(w_dil_p, w_dil_c, WGh, WGl);
  k_split<<<320, 256, 0, stream>>>(w_res, WRh, WRl, 81920);
  k_split_hi<<<1280, 256, 0, stream>>>(w_skip, WSh, 327680);
  k_split<<<256, 256, 0, stream>>>(w_relu, WLh, WLl, 65536);
  k_split<<<256, 256, 0, stream>>>(w_out, WOh, WOl, 65536);
  k_zero_guard<<<2048, 256, 0, stream>>>(hA, hB);
  k_bsum<<<1, 256, 0, stream>>>(b_skip, bsum);

  k_head_in<<<B_ * NBT, 512, 0, stream>>>(x, WPh, WPl, b_pre0, hA);

  const short* hin = hA;
  short* houtp = hB;
  for (int l = 0; l < NLAY; ++l) {
    int d = 1 << (l % 10);
    k_layer2<<<B_ * NBT, 512, 0, stream>>>(
        hin, houtp,
        GBUF + (size_t)l * B_ * T_ * 64,
        WGh + (size_t)l*16384, WGl + (size_t)l*16384,
        WRh + (size_t)l*4096,  WRl + (size_t)l*4096,
        bias_h + (size_t)l*128, b_res + (size_t)l*64, d);
    const short* tmp = hin;
    hin = houtp;
    houtp = (short*)tmp;
  }

  k_head_fused<<<B_ * NBT, 512, 0, stream>>>(
      out, GBUF, WSh, bsum, WLh, WLl, b_relu, WOh, WOl, b_out);
}